// Round 1
// baseline (1081.167 us; speedup 1.0000x reference)
//
#include <hip/hip_runtime.h>
#include <hip/hip_bf16.h>

typedef __bf16 bf16_t;
typedef __bf16 bf16x8 __attribute__((ext_vector_type(8)));
typedef float floatx4 __attribute__((ext_vector_type(4)));

#define M_TOK 8192
#define K_DIM 4096
#define N_OUT 4096
#define NEXP  8
#define LRANK 16
#define KEXT  128
#define SCALING 2.0f

// ---------------------------------------------------------------- helpers

__device__ __forceinline__ void pack4(bf16_t* dst, float4 v) {
    union { bf16_t h[4]; uint2 u; } t;
    t.h[0] = (bf16_t)v.x; t.h[1] = (bf16_t)v.y;
    t.h[2] = (bf16_t)v.z; t.h[3] = (bf16_t)v.w;
    *(uint2*)dst = t.u;   // 8B aligned by construction
}

// ---------------------------------------------------------------- K0: repack lora_B -> Bflat[o][e*16+r] bf16

__global__ __launch_bounds__(256) void prep_bflat(const float* __restrict__ loraB,
                                                  bf16_t* __restrict__ bflat) {
    int g = blockIdx.x * 256 + threadIdx.x;        // < 4096*128
    int o = g >> 7, j = g & 127;
    int e = j >> 4, r = j & 15;
    bflat[g] = (bf16_t)loraB[((size_t)e * N_OUT + o) * LRANK + r];
}

// ---------------------------------------------------------------- K1: router (fp32, exact-ish)

__global__ __launch_bounds__(256) void gate_kernel(const float* __restrict__ x,
                                                   const float* __restrict__ routeW,
                                                   float* __restrict__ rw_out,    // [M,8]
                                                   float* __restrict__ gate_out)  // [M,8]
{
    int wave = threadIdx.x >> 6;
    int lane = threadIdx.x & 63;
    int t = blockIdx.x * 4 + wave;
    const float4* xp = (const float4*)(x + (size_t)t * K_DIM);
    float acc[NEXP];
    #pragma unroll
    for (int e = 0; e < NEXP; ++e) acc[e] = 0.f;

    #pragma unroll 4
    for (int it = 0; it < K_DIM / 256; ++it) {
        float4 xv = xp[it * 64 + lane];
        #pragma unroll
        for (int e = 0; e < NEXP; ++e) {
            float4 wv = ((const float4*)(routeW + (size_t)e * K_DIM))[it * 64 + lane];
            acc[e] += xv.x * wv.x + xv.y * wv.y + xv.z * wv.z + xv.w * wv.w;
        }
    }
    #pragma unroll
    for (int e = 0; e < NEXP; ++e)
        for (int off = 32; off > 0; off >>= 1)
            acc[e] += __shfl_xor(acc[e], off, 64);

    if (lane == 0) {
        float mx = acc[0];
        #pragma unroll
        for (int e = 1; e < NEXP; ++e) mx = fmaxf(mx, acc[e]);
        float p[NEXP], s = 0.f;
        #pragma unroll
        for (int e = 0; e < NEXP; ++e) { p[e] = expf(acc[e] - mx); s += p[e]; }
        float inv_s = 1.0f / s;
        #pragma unroll
        for (int e = 0; e < NEXP; ++e) p[e] *= inv_s;
        // top-2 (first index wins ties, like lax.top_k)
        int i0 = 0;
        #pragma unroll
        for (int e = 1; e < NEXP; ++e) if (p[e] > p[i0]) i0 = e;
        int i1 = (i0 == 0) ? 1 : 0;
        #pragma unroll
        for (int e = 0; e < NEXP; ++e) { if (e == i0 || e == i1) continue; if (p[e] > p[i1]) i1 = e; }
        float v0 = p[i0], v1 = p[i1];
        float inv = 1.0f / (v0 + v1 + 1e-9f);
        float r[NEXP];
        #pragma unroll
        for (int e = 0; e < NEXP; ++e) r[e] = 0.f;
        r[i0] = v0 * inv; r[i1] = v1 * inv;
        #pragma unroll
        for (int e = 0; e < NEXP; ++e) {
            gate_out[(size_t)t * NEXP + e] = acc[e];
            rw_out[(size_t)t * NEXP + e]  = r[e];
        }
    }
}

// ---------------------------------------------------------------- K2: h = x @ lora_A^T, gated, -> hw bf16 [M][128]

__global__ __launch_bounds__(256) void h_kernel(const float* __restrict__ x,
                                                const float* __restrict__ loraA,  // [128][4096]
                                                const float* __restrict__ rw,     // [M][8]
                                                bf16_t* __restrict__ hw)          // [M][128]
{
    __shared__ bf16_t As[32][40];
    __shared__ bf16_t Bs[128][40];
    int tid = threadIdx.x;
    int wave = tid >> 6, lane = tid & 63;
    int lrow = lane & 15, lq = lane >> 4;
    int m0 = blockIdx.x * 32;
    floatx4 acc[2][2] = {};
    int rb = tid >> 1, cb = (tid & 1) * 16;

    for (int k0 = 0; k0 < K_DIM; k0 += 32) {
        if (tid < 64) {
            const float* srcA = x + (size_t)(m0 + rb) * K_DIM + k0 + cb;
            #pragma unroll
            for (int q = 0; q < 4; ++q) pack4(&As[rb][cb + q * 4], ((const float4*)srcA)[q]);
        }
        {
            const float* srcB = loraA + (size_t)rb * K_DIM + k0 + cb;
            #pragma unroll
            for (int q = 0; q < 4; ++q) pack4(&Bs[rb][cb + q * 4], ((const float4*)srcB)[q]);
        }
        __syncthreads();
        bf16x8 af[2], bfr[2];
        #pragma unroll
        for (int mi = 0; mi < 2; ++mi) af[mi] = *(const bf16x8*)&As[mi * 16 + lrow][lq * 8];
        #pragma unroll
        for (int ni = 0; ni < 2; ++ni) bfr[ni] = *(const bf16x8*)&Bs[wave * 32 + ni * 16 + lrow][lq * 8];
        #pragma unroll
        for (int mi = 0; mi < 2; ++mi)
            #pragma unroll
            for (int ni = 0; ni < 2; ++ni)
                acc[mi][ni] = __builtin_amdgcn_mfma_f32_16x16x32_bf16(af[mi], bfr[ni], acc[mi][ni], 0, 0, 0);
        __syncthreads();
    }
    #pragma unroll
    for (int mi = 0; mi < 2; ++mi)
        #pragma unroll
        for (int ni = 0; ni < 2; ++ni)
            #pragma unroll
            for (int reg = 0; reg < 4; ++reg) {
                int t = m0 + mi * 16 + lq * 4 + reg;
                int j = wave * 32 + ni * 16 + lrow;
                float g = rw[(size_t)t * NEXP + (j >> 4)] * SCALING;
                hw[(size_t)t * KEXT + j] = (bf16_t)(acc[mi][ni][reg] * g);
            }
}

// ---------------------------------------------------------------- K3: result = x@W^T + bias + hw@Bflat^T

__device__ __forceinline__ void mma_step(const bf16_t (*As)[40], const bf16_t (*Bs)[40],
                                         floatx4 acc[4][4], int wm, int wn, int lrow, int lq) {
    bf16x8 af[4], bfr[4];
    #pragma unroll
    for (int mi = 0; mi < 4; ++mi) af[mi] = *(const bf16x8*)&As[wm + mi * 16 + lrow][lq * 8];
    #pragma unroll
    for (int ni = 0; ni < 4; ++ni) bfr[ni] = *(const bf16x8*)&Bs[wn + ni * 16 + lrow][lq * 8];
    #pragma unroll
    for (int mi = 0; mi < 4; ++mi)
        #pragma unroll
        for (int ni = 0; ni < 4; ++ni)
            acc[mi][ni] = __builtin_amdgcn_mfma_f32_16x16x32_bf16(af[mi], bfr[ni], acc[mi][ni], 0, 0, 0);
}

__global__ __launch_bounds__(256) void main_gemm(const float* __restrict__ x,
                                                 const float* __restrict__ W,
                                                 const float* __restrict__ bias,
                                                 const bf16_t* __restrict__ hw,
                                                 const bf16_t* __restrict__ bflat,
                                                 float* __restrict__ out)
{
    __shared__ bf16_t As[128][40];
    __shared__ bf16_t Bs[128][40];
    int tid = threadIdx.x, lane = tid & 63, wave = tid >> 6;
    int lrow = lane & 15, lq = lane >> 4;
    int wm = (wave >> 1) * 64, wn = (wave & 1) * 64;
    int tm = blockIdx.y * 128, tn = blockIdx.x * 128;
    floatx4 acc[4][4] = {};
    int rb = tid >> 1, cb = (tid & 1) * 16;
    const float* gA = x + (size_t)(tm + rb) * K_DIM + cb;
    const float* gB = W + (size_t)(tn + rb) * K_DIM + cb;

    for (int k0 = 0; k0 < K_DIM; k0 += 32) {
        #pragma unroll
        for (int q = 0; q < 4; ++q) {
            pack4(&As[rb][cb + q * 4], ((const float4*)(gA + k0))[q]);
            pack4(&Bs[rb][cb + q * 4], ((const float4*)(gB + k0))[q]);
        }
        __syncthreads();
        mma_step(As, Bs, acc, wm, wn, lrow, lq);
        __syncthreads();
    }

    // K-extension: 128 more K from hw (A side, bf16) and bflat (B side, bf16)
    const bf16_t* eA = hw    + (size_t)(tm + rb) * KEXT + cb;
    const bf16_t* eB = bflat + (size_t)(tn + rb) * KEXT + cb;
    for (int k0 = 0; k0 < KEXT; k0 += 32) {
        *(uint4*)&As[rb][cb]     = *(const uint4*)(eA + k0);
        *(uint4*)&As[rb][cb + 8] = *(const uint4*)(eA + k0 + 8);
        *(uint4*)&Bs[rb][cb]     = *(const uint4*)(eB + k0);
        *(uint4*)&Bs[rb][cb + 8] = *(const uint4*)(eB + k0 + 8);
        __syncthreads();
        mma_step(As, Bs, acc, wm, wn, lrow, lq);
        __syncthreads();
    }

    #pragma unroll
    for (int mi = 0; mi < 4; ++mi)
        #pragma unroll
        for (int ni = 0; ni < 4; ++ni) {
            int row = tm + wm + mi * 16 + lq * 4;
            int col = tn + wn + ni * 16 + lrow;
            float b = bias[col];
            #pragma unroll
            for (int reg = 0; reg < 4; ++reg)
                out[(size_t)(row + reg) * N_OUT + col] = acc[mi][ni][reg] + b;
        }
}

// ---------------------------------------------------------------- launch

extern "C" void kernel_launch(void* const* d_in, const int* in_sizes, int n_in,
                              void* d_out, int out_size, void* d_ws, size_t ws_size,
                              hipStream_t stream) {
    const float* x      = (const float*)d_in[0];
    const float* W      = (const float*)d_in[1];
    const float* bias   = (const float*)d_in[2];
    const float* routeW = (const float*)d_in[3];
    const float* loraA  = (const float*)d_in[4];   // [8][16][4096] == [128][4096]
    const float* loraB  = (const float*)d_in[5];   // [8][4096][16]

    float* out0 = (float*)d_out;                         // result
    float* out1 = out0 + (size_t)M_TOK * N_OUT;          // routing_weight
    float* out2 = out1 + (size_t)M_TOK * NEXP;           // gate_score

    bf16_t* bflat = (bf16_t*)d_ws;                       // [4096*128] = 1 MB
    bf16_t* hw    = bflat + (size_t)N_OUT * KEXT;        // [8192*128] = 2 MB

    hipLaunchKernelGGL(prep_bflat, dim3((N_OUT * KEXT) / 256), dim3(256), 0, stream, loraB, bflat);
    hipLaunchKernelGGL(gate_kernel, dim3(M_TOK / 4), dim3(256), 0, stream, x, routeW, out1, out2);
    hipLaunchKernelGGL(h_kernel, dim3(M_TOK / 32), dim3(256), 0, stream, x, loraA, out1, hw);
    hipLaunchKernelGGL(main_gemm, dim3(N_OUT / 128, M_TOK / 128), dim3(256), 0, stream,
                       x, W, bias, hw, bflat, out0);
}

// Round 2
// 782.271 us; speedup vs baseline: 1.3821x; 1.3821x over previous
//
#include <hip/hip_runtime.h>
#include <hip/hip_bf16.h>

typedef __bf16 bf16_t;
typedef __bf16 bf16x8 __attribute__((ext_vector_type(8)));
typedef float floatx4 __attribute__((ext_vector_type(4)));

#define M_TOK 8192
#define K_DIM 4096
#define N_OUT 4096
#define NEXP  8
#define LRANK 16
#define KEXT  128
#define SCALING 2.0f

// async 16B global -> LDS (wave-uniform LDS base + lane*16)
#define GLOAD_LDS16(g, l) \
    __builtin_amdgcn_global_load_lds((const __attribute__((address_space(1))) void*)(g), \
                                     (__attribute__((address_space(3))) void*)(l), 16, 0, 0)

// ---------------------------------------------------------------- helpers

__device__ __forceinline__ void pack4(bf16_t* dst, float4 v) {
    union { bf16_t h[4]; uint2 u; } t;
    t.h[0] = (bf16_t)v.x; t.h[1] = (bf16_t)v.y;
    t.h[2] = (bf16_t)v.z; t.h[3] = (bf16_t)v.w;
    *(uint2*)dst = t.u;
}

// ---------------------------------------------------------------- cvt fp32 -> bf16, 8 elems/thread

__global__ __launch_bounds__(256) void cvt_bf16(const float* __restrict__ src,
                                                bf16_t* __restrict__ dst) {
    size_t i = (size_t)blockIdx.x * 256 + threadIdx.x;
    float4 a = ((const float4*)src)[i * 2];
    float4 b = ((const float4*)src)[i * 2 + 1];
    union { bf16_t h[8]; uint4 u; } t;
    t.h[0] = (bf16_t)a.x; t.h[1] = (bf16_t)a.y; t.h[2] = (bf16_t)a.z; t.h[3] = (bf16_t)a.w;
    t.h[4] = (bf16_t)b.x; t.h[5] = (bf16_t)b.y; t.h[6] = (bf16_t)b.z; t.h[7] = (bf16_t)b.w;
    ((uint4*)dst)[i] = t.u;
}

// ---------------------------------------------------------------- K0: repack lora_B -> Bflat[o][e*16+r] bf16

__global__ __launch_bounds__(256) void prep_bflat(const float* __restrict__ loraB,
                                                  bf16_t* __restrict__ bflat) {
    int g = blockIdx.x * 256 + threadIdx.x;        // < 4096*128
    int o = g >> 7, j = g & 127;
    int e = j >> 4, r = j & 15;
    bflat[g] = (bf16_t)loraB[((size_t)e * N_OUT + o) * LRANK + r];
}

// ---------------------------------------------------------------- K1: router (fp32 exact path)

__global__ __launch_bounds__(256) void gate_kernel(const float* __restrict__ x,
                                                   const float* __restrict__ routeW,
                                                   float* __restrict__ rw_out,    // [M,8]
                                                   float* __restrict__ gate_out)  // [M,8]
{
    int wave = threadIdx.x >> 6;
    int lane = threadIdx.x & 63;
    int t = blockIdx.x * 4 + wave;
    const float4* xp = (const float4*)(x + (size_t)t * K_DIM);
    float acc[NEXP];
    #pragma unroll
    for (int e = 0; e < NEXP; ++e) acc[e] = 0.f;

    #pragma unroll 4
    for (int it = 0; it < K_DIM / 256; ++it) {
        float4 xv = xp[it * 64 + lane];
        #pragma unroll
        for (int e = 0; e < NEXP; ++e) {
            float4 wv = ((const float4*)(routeW + (size_t)e * K_DIM))[it * 64 + lane];
            acc[e] += xv.x * wv.x + xv.y * wv.y + xv.z * wv.z + xv.w * wv.w;
        }
    }
    #pragma unroll
    for (int e = 0; e < NEXP; ++e)
        for (int off = 32; off > 0; off >>= 1)
            acc[e] += __shfl_xor(acc[e], off, 64);

    if (lane == 0) {
        float mx = acc[0];
        #pragma unroll
        for (int e = 1; e < NEXP; ++e) mx = fmaxf(mx, acc[e]);
        float p[NEXP], s = 0.f;
        #pragma unroll
        for (int e = 0; e < NEXP; ++e) { p[e] = expf(acc[e] - mx); s += p[e]; }
        float inv_s = 1.0f / s;
        #pragma unroll
        for (int e = 0; e < NEXP; ++e) p[e] *= inv_s;
        int i0 = 0;
        #pragma unroll
        for (int e = 1; e < NEXP; ++e) if (p[e] > p[i0]) i0 = e;
        int i1 = (i0 == 0) ? 1 : 0;
        #pragma unroll
        for (int e = 0; e < NEXP; ++e) { if (e == i0 || e == i1) continue; if (p[e] > p[i1]) i1 = e; }
        float v0 = p[i0], v1 = p[i1];
        float inv = 1.0f / (v0 + v1 + 1e-9f);
        float r[NEXP];
        #pragma unroll
        for (int e = 0; e < NEXP; ++e) r[e] = 0.f;
        r[i0] = v0 * inv; r[i1] = v1 * inv;
        #pragma unroll
        for (int e = 0; e < NEXP; ++e) {
            gate_out[(size_t)t * NEXP + e] = acc[e];
            rw_out[(size_t)t * NEXP + e]  = r[e];
        }
    }
}

// ================================================================ FAST PATH
// K2f: h = xb @ aflat^T gated -> hw bf16 [M][128]. BM=64, BN=128, BK=32.

__global__ __launch_bounds__(256) void h_kernel_fast(const bf16_t* __restrict__ xb,
                                                     const bf16_t* __restrict__ aflat, // [128][4096] bf16
                                                     const float* __restrict__ rw,
                                                     bf16_t* __restrict__ hw)
{
    __shared__ bf16_t As[64 * 32];
    __shared__ bf16_t Bs[128 * 32];
    int tid = threadIdx.x, lane = tid & 63, wave = tid >> 6;
    int lrow = lane & 15, lq = lane >> 4;
    int wm = (wave >> 1) * 32, wn = (wave & 1) * 64;
    int m0 = blockIdx.x * 64;
    floatx4 acc[2][4] = {};

    int r0 = tid >> 2;                 // 0..63
    int cg = (tid & 3) * 8;            // col elem offset
    const bf16_t* gA  = xb    + (size_t)(m0 + r0) * K_DIM + cg;
    const bf16_t* gB0 = aflat + (size_t)r0 * K_DIM + cg;
    const bf16_t* gB1 = aflat + (size_t)(64 + r0) * K_DIM + cg;
    bf16_t* lA  = As + wave * 512;
    bf16_t* lB0 = Bs + wave * 512;
    bf16_t* lB1 = Bs + 2048 + wave * 512;

    for (int k0 = 0; k0 < K_DIM; k0 += 32) {
        GLOAD_LDS16(gA + k0, lA);
        GLOAD_LDS16(gB0 + k0, lB0);
        GLOAD_LDS16(gB1 + k0, lB1);
        __syncthreads();
        bf16x8 af[2], bfr[4];
        #pragma unroll
        for (int mi = 0; mi < 2; ++mi) af[mi] = *(const bf16x8*)(As + (wm + mi * 16 + lrow) * 32 + lq * 8);
        #pragma unroll
        for (int ni = 0; ni < 4; ++ni) bfr[ni] = *(const bf16x8*)(Bs + (wn + ni * 16 + lrow) * 32 + lq * 8);
        #pragma unroll
        for (int mi = 0; mi < 2; ++mi)
            #pragma unroll
            for (int ni = 0; ni < 4; ++ni)
                acc[mi][ni] = __builtin_amdgcn_mfma_f32_16x16x32_bf16(af[mi], bfr[ni], acc[mi][ni], 0, 0, 0);
        __syncthreads();
    }
    #pragma unroll
    for (int mi = 0; mi < 2; ++mi)
        #pragma unroll
        for (int ni = 0; ni < 4; ++ni)
            #pragma unroll
            for (int reg = 0; reg < 4; ++reg) {
                int t = m0 + wm + mi * 16 + lq * 4 + reg;
                int j = wn + ni * 16 + lrow;
                float g = rw[(size_t)t * NEXP + (j >> 4)] * SCALING;
                hw[(size_t)t * KEXT + j] = (bf16_t)(acc[mi][ni][reg] * g);
            }
}

// K3f: result = xb@Wb^T + bias + hw@bflat^T. 128x128 tile, BK=32, async staging.

__global__ __launch_bounds__(256) void main_gemm_fast(const bf16_t* __restrict__ xb,
                                                      const bf16_t* __restrict__ Wb,
                                                      const float* __restrict__ bias,
                                                      const bf16_t* __restrict__ hw,
                                                      const bf16_t* __restrict__ bflat,
                                                      float* __restrict__ out)
{
    __shared__ bf16_t As[128 * 32];
    __shared__ bf16_t Bs[128 * 32];
    int tid = threadIdx.x, lane = tid & 63, wave = tid >> 6;
    int lrow = lane & 15, lq = lane >> 4;
    int wm = (wave >> 1) * 64, wn = (wave & 1) * 64;
    int tm = blockIdx.y * 128, tn = blockIdx.x * 128;
    floatx4 acc[4][4] = {};

    int r0 = tid >> 2;                 // 0..63
    int cg = (tid & 3) * 8;
    const bf16_t* gA0 = xb + (size_t)(tm + r0) * K_DIM + cg;
    const bf16_t* gA1 = xb + (size_t)(tm + 64 + r0) * K_DIM + cg;
    const bf16_t* gB0 = Wb + (size_t)(tn + r0) * K_DIM + cg;
    const bf16_t* gB1 = Wb + (size_t)(tn + 64 + r0) * K_DIM + cg;
    bf16_t* lA0 = As + wave * 512;
    bf16_t* lA1 = As + 2048 + wave * 512;
    bf16_t* lB0 = Bs + wave * 512;
    bf16_t* lB1 = Bs + 2048 + wave * 512;

    for (int k0 = 0; k0 < K_DIM; k0 += 32) {
        GLOAD_LDS16(gA0 + k0, lA0);
        GLOAD_LDS16(gA1 + k0, lA1);
        GLOAD_LDS16(gB0 + k0, lB0);
        GLOAD_LDS16(gB1 + k0, lB1);
        __syncthreads();
        bf16x8 af[4], bfr[4];
        #pragma unroll
        for (int mi = 0; mi < 4; ++mi) af[mi] = *(const bf16x8*)(As + (wm + mi * 16 + lrow) * 32 + lq * 8);
        #pragma unroll
        for (int ni = 0; ni < 4; ++ni) bfr[ni] = *(const bf16x8*)(Bs + (wn + ni * 16 + lrow) * 32 + lq * 8);
        #pragma unroll
        for (int mi = 0; mi < 4; ++mi)
            #pragma unroll
            for (int ni = 0; ni < 4; ++ni)
                acc[mi][ni] = __builtin_amdgcn_mfma_f32_16x16x32_bf16(af[mi], bfr[ni], acc[mi][ni], 0, 0, 0);
        __syncthreads();
    }

    // K-extension: 128 more K from hw (A) and bflat (B), stride KEXT
    {
        const bf16_t* eA0 = hw    + (size_t)(tm + r0) * KEXT + cg;
        const bf16_t* eA1 = hw    + (size_t)(tm + 64 + r0) * KEXT + cg;
        const bf16_t* eB0 = bflat + (size_t)(tn + r0) * KEXT + cg;
        const bf16_t* eB1 = bflat + (size_t)(tn + 64 + r0) * KEXT + cg;
        for (int k0 = 0; k0 < KEXT; k0 += 32) {
            GLOAD_LDS16(eA0 + k0, lA0);
            GLOAD_LDS16(eA1 + k0, lA1);
            GLOAD_LDS16(eB0 + k0, lB0);
            GLOAD_LDS16(eB1 + k0, lB1);
            __syncthreads();
            bf16x8 af[4], bfr[4];
            #pragma unroll
            for (int mi = 0; mi < 4; ++mi) af[mi] = *(const bf16x8*)(As + (wm + mi * 16 + lrow) * 32 + lq * 8);
            #pragma unroll
            for (int ni = 0; ni < 4; ++ni) bfr[ni] = *(const bf16x8*)(Bs + (wn + ni * 16 + lrow) * 32 + lq * 8);
            #pragma unroll
            for (int mi = 0; mi < 4; ++mi)
                #pragma unroll
                for (int ni = 0; ni < 4; ++ni)
                    acc[mi][ni] = __builtin_amdgcn_mfma_f32_16x16x32_bf16(af[mi], bfr[ni], acc[mi][ni], 0, 0, 0);
            __syncthreads();
        }
    }

    #pragma unroll
    for (int mi = 0; mi < 4; ++mi)
        #pragma unroll
        for (int ni = 0; ni < 4; ++ni) {
            int row = tm + wm + mi * 16 + lq * 4;
            int col = tn + wn + ni * 16 + lrow;
            float b = bias[col];
            #pragma unroll
            for (int reg = 0; reg < 4; ++reg)
                out[(size_t)(row + reg) * N_OUT + col] = acc[mi][ni][reg] + b;
        }
}

// ================================================================ FALLBACK PATH (round-1, known-good)

__global__ __launch_bounds__(256) void h_kernel(const float* __restrict__ x,
                                                const float* __restrict__ loraA,
                                                const float* __restrict__ rw,
                                                bf16_t* __restrict__ hw)
{
    __shared__ bf16_t As[32][40];
    __shared__ bf16_t Bs[128][40];
    int tid = threadIdx.x;
    int wave = tid >> 6, lane = tid & 63;
    int lrow = lane & 15, lq = lane >> 4;
    int m0 = blockIdx.x * 32;
    floatx4 acc[2][2] = {};
    int rb = tid >> 1, cb = (tid & 1) * 16;

    for (int k0 = 0; k0 < K_DIM; k0 += 32) {
        if (tid < 64) {
            const float* srcA = x + (size_t)(m0 + rb) * K_DIM + k0 + cb;
            #pragma unroll
            for (int q = 0; q < 4; ++q) pack4(&As[rb][cb + q * 4], ((const float4*)srcA)[q]);
        }
        {
            const float* srcB = loraA + (size_t)rb * K_DIM + k0 + cb;
            #pragma unroll
            for (int q = 0; q < 4; ++q) pack4(&Bs[rb][cb + q * 4], ((const float4*)srcB)[q]);
        }
        __syncthreads();
        bf16x8 af[2], bfr[2];
        #pragma unroll
        for (int mi = 0; mi < 2; ++mi) af[mi] = *(const bf16x8*)&As[mi * 16 + lrow][lq * 8];
        #pragma unroll
        for (int ni = 0; ni < 2; ++ni) bfr[ni] = *(const bf16x8*)&Bs[wave * 32 + ni * 16 + lrow][lq * 8];
        #pragma unroll
        for (int mi = 0; mi < 2; ++mi)
            #pragma unroll
            for (int ni = 0; ni < 2; ++ni)
                acc[mi][ni] = __builtin_amdgcn_mfma_f32_16x16x32_bf16(af[mi], bfr[ni], acc[mi][ni], 0, 0, 0);
        __syncthreads();
    }
    #pragma unroll
    for (int mi = 0; mi < 2; ++mi)
        #pragma unroll
        for (int ni = 0; ni < 2; ++ni)
            #pragma unroll
            for (int reg = 0; reg < 4; ++reg) {
                int t = m0 + mi * 16 + lq * 4 + reg;
                int j = wave * 32 + ni * 16 + lrow;
                float g = rw[(size_t)t * NEXP + (j >> 4)] * SCALING;
                hw[(size_t)t * KEXT + j] = (bf16_t)(acc[mi][ni][reg] * g);
            }
}

__device__ __forceinline__ void mma_step(const bf16_t (*As)[40], const bf16_t (*Bs)[40],
                                         floatx4 acc[4][4], int wm, int wn, int lrow, int lq) {
    bf16x8 af[4], bfr[4];
    #pragma unroll
    for (int mi = 0; mi < 4; ++mi) af[mi] = *(const bf16x8*)&As[wm + mi * 16 + lrow][lq * 8];
    #pragma unroll
    for (int ni = 0; ni < 4; ++ni) bfr[ni] = *(const bf16x8*)&Bs[wn + ni * 16 + lrow][lq * 8];
    #pragma unroll
    for (int mi = 0; mi < 4; ++mi)
        #pragma unroll
        for (int ni = 0; ni < 4; ++ni)
            acc[mi][ni] = __builtin_amdgcn_mfma_f32_16x16x32_bf16(af[mi], bfr[ni], acc[mi][ni], 0, 0, 0);
}

__global__ __launch_bounds__(256) void main_gemm(const float* __restrict__ x,
                                                 const float* __restrict__ W,
                                                 const float* __restrict__ bias,
                                                 const bf16_t* __restrict__ hw,
                                                 const bf16_t* __restrict__ bflat,
                                                 float* __restrict__ out)
{
    __shared__ bf16_t As[128][40];
    __shared__ bf16_t Bs[128][40];
    int tid = threadIdx.x, lane = tid & 63, wave = tid >> 6;
    int lrow = lane & 15, lq = lane >> 4;
    int wm = (wave >> 1) * 64, wn = (wave & 1) * 64;
    int tm = blockIdx.y * 128, tn = blockIdx.x * 128;
    floatx4 acc[4][4] = {};
    int rb = tid >> 1, cb = (tid & 1) * 16;
    const float* gA = x + (size_t)(tm + rb) * K_DIM + cb;
    const float* gB = W + (size_t)(tn + rb) * K_DIM + cb;

    for (int k0 = 0; k0 < K_DIM; k0 += 32) {
        #pragma unroll
        for (int q = 0; q < 4; ++q) {
            pack4(&As[rb][cb + q * 4], ((const float4*)(gA + k0))[q]);
            pack4(&Bs[rb][cb + q * 4], ((const float4*)(gB + k0))[q]);
        }
        __syncthreads();
        mma_step(As, Bs, acc, wm, wn, lrow, lq);
        __syncthreads();
    }
    const bf16_t* eA = hw    + (size_t)(tm + rb) * KEXT + cb;
    const bf16_t* eB = bflat + (size_t)(tn + rb) * KEXT + cb;
    for (int k0 = 0; k0 < KEXT; k0 += 32) {
        *(uint4*)&As[rb][cb]     = *(const uint4*)(eA + k0);
        *(uint4*)&As[rb][cb + 8] = *(const uint4*)(eA + k0 + 8);
        *(uint4*)&Bs[rb][cb]     = *(const uint4*)(eB + k0);
        *(uint4*)&Bs[rb][cb + 8] = *(const uint4*)(eB + k0 + 8);
        __syncthreads();
        mma_step(As, Bs, acc, wm, wn, lrow, lq);
        __syncthreads();
    }

    #pragma unroll
    for (int mi = 0; mi < 4; ++mi)
        #pragma unroll
        for (int ni = 0; ni < 4; ++ni) {
            int row = tm + wm + mi * 16 + lq * 4;
            int col = tn + wn + ni * 16 + lrow;
            float b = bias[col];
            #pragma unroll
            for (int reg = 0; reg < 4; ++reg)
                out[(size_t)(row + reg) * N_OUT + col] = acc[mi][ni][reg] + b;
        }
}

// ---------------------------------------------------------------- launch

extern "C" void kernel_launch(void* const* d_in, const int* in_sizes, int n_in,
                              void* d_out, int out_size, void* d_ws, size_t ws_size,
                              hipStream_t stream) {
    const float* x      = (const float*)d_in[0];
    const float* W      = (const float*)d_in[1];
    const float* bias   = (const float*)d_in[2];
    const float* routeW = (const float*)d_in[3];
    const float* loraA  = (const float*)d_in[4];   // [8][16][4096] == [128][4096]
    const float* loraB  = (const float*)d_in[5];   // [8][4096][16]

    float* out0 = (float*)d_out;
    float* out1 = out0 + (size_t)M_TOK * N_OUT;
    float* out2 = out1 + (size_t)M_TOK * NEXP;

    // ws layout (fast path): xb 64MB | Wb 32MB | aflat 1MB | bflat 1MB | hw 2MB = 100MB
    size_t need = ((size_t)M_TOK * K_DIM + (size_t)N_OUT * K_DIM +
                   (size_t)KEXT * K_DIM + (size_t)N_OUT * KEXT +
                   (size_t)M_TOK * KEXT) * sizeof(bf16_t);

    if (ws_size >= need) {
        bf16_t* xb    = (bf16_t*)d_ws;
        bf16_t* Wb    = xb + (size_t)M_TOK * K_DIM;
        bf16_t* aflat = Wb + (size_t)N_OUT * K_DIM;
        bf16_t* bflat = aflat + (size_t)KEXT * K_DIM;
        bf16_t* hw    = bflat + (size_t)N_OUT * KEXT;

        hipLaunchKernelGGL(cvt_bf16, dim3((M_TOK * (size_t)K_DIM) / 8 / 256), dim3(256), 0, stream, x, xb);
        hipLaunchKernelGGL(cvt_bf16, dim3((N_OUT * (size_t)K_DIM) / 8 / 256), dim3(256), 0, stream, W, Wb);
        hipLaunchKernelGGL(cvt_bf16, dim3((KEXT * (size_t)K_DIM) / 8 / 256), dim3(256), 0, stream, loraA, aflat);
        hipLaunchKernelGGL(prep_bflat, dim3((N_OUT * KEXT) / 256), dim3(256), 0, stream, loraB, bflat);
        hipLaunchKernelGGL(gate_kernel, dim3(M_TOK / 4), dim3(256), 0, stream, x, routeW, out1, out2);
        hipLaunchKernelGGL(h_kernel_fast, dim3(M_TOK / 64), dim3(256), 0, stream, xb, aflat, out1, hw);
        hipLaunchKernelGGL(main_gemm_fast, dim3(N_OUT / 128, M_TOK / 128), dim3(256), 0, stream,
                           xb, Wb, bias, hw, bflat, out0);
    } else {
        bf16_t* bflat = (bf16_t*)d_ws;
        bf16_t* hw    = bflat + (size_t)N_OUT * KEXT;
        hipLaunchKernelGGL(prep_bflat, dim3((N_OUT * KEXT) / 256), dim3(256), 0, stream, loraB, bflat);
        hipLaunchKernelGGL(gate_kernel, dim3(M_TOK / 4), dim3(256), 0, stream, x, routeW, out1, out2);
        hipLaunchKernelGGL(h_kernel, dim3(M_TOK / 32), dim3(256), 0, stream, x, loraA, out1, hw);
        hipLaunchKernelGGL(main_gemm, dim3(N_OUT / 128, M_TOK / 128), dim3(256), 0, stream,
                           x, W, bias, hw, bflat, out0);
    }
}

// Round 3
// 739.605 us; speedup vs baseline: 1.4618x; 1.0577x over previous
//
#include <hip/hip_runtime.h>
#include <hip/hip_bf16.h>

typedef __bf16 bf16_t;
typedef __bf16 bf16x8 __attribute__((ext_vector_type(8)));
typedef float floatx4 __attribute__((ext_vector_type(4)));

#define M_TOK 8192
#define K_DIM 4096
#define N_OUT 4096
#define NEXP  8
#define LRANK 16
#define KEXT  128
#define SCALING 2.0f

// async 16B global -> LDS. LDS arg is wave-uniform base; HW scatters lane i to base + i*16B.
#define GLOAD_LDS16(g, l) \
    __builtin_amdgcn_global_load_lds((const __attribute__((address_space(1))) void*)(g), \
                                     (__attribute__((address_space(3))) void*)(l), 16, 0, 0)

// ---------------------------------------------------------------- helpers

__device__ __forceinline__ void pack4(bf16_t* dst, float4 v) {
    union { bf16_t h[4]; uint2 u; } t;
    t.h[0] = (bf16_t)v.x; t.h[1] = (bf16_t)v.y;
    t.h[2] = (bf16_t)v.z; t.h[3] = (bf16_t)v.w;
    *(uint2*)dst = t.u;
}

// ---------------------------------------------------------------- cvt fp32 -> bf16, 8 elems/thread

__global__ __launch_bounds__(256) void cvt_bf16(const float* __restrict__ src,
                                                bf16_t* __restrict__ dst) {
    size_t i = (size_t)blockIdx.x * 256 + threadIdx.x;
    float4 a = ((const float4*)src)[i * 2];
    float4 b = ((const float4*)src)[i * 2 + 1];
    union { bf16_t h[8]; uint4 u; } t;
    t.h[0] = (bf16_t)a.x; t.h[1] = (bf16_t)a.y; t.h[2] = (bf16_t)a.z; t.h[3] = (bf16_t)a.w;
    t.h[4] = (bf16_t)b.x; t.h[5] = (bf16_t)b.y; t.h[6] = (bf16_t)b.z; t.h[7] = (bf16_t)b.w;
    ((uint4*)dst)[i] = t.u;
}

// ---------------------------------------------------------------- K0: repack lora_B -> Bflat[o][e*16+r] bf16

__global__ __launch_bounds__(256) void prep_bflat(const float* __restrict__ loraB,
                                                  bf16_t* __restrict__ bflat) {
    int g = blockIdx.x * 256 + threadIdx.x;        // < 4096*128
    int o = g >> 7, j = g & 127;
    int e = j >> 4, r = j & 15;
    bflat[g] = (bf16_t)loraB[((size_t)e * N_OUT + o) * LRANK + r];
}

// ---------------------------------------------------------------- K1: router fused with x->bf16 conversion
// One wave per token. Reads x fp32 once; emits xb bf16 + gate_score + routing_weight.

__global__ __launch_bounds__(256) void gate_cvt_kernel(const float* __restrict__ x,
                                                       const float* __restrict__ routeW,
                                                       bf16_t* __restrict__ xb,
                                                       float* __restrict__ rw_out,    // [M,8]
                                                       float* __restrict__ gate_out)  // [M,8]
{
    int wave = threadIdx.x >> 6;
    int lane = threadIdx.x & 63;
    int t = blockIdx.x * 4 + wave;
    const float4* xp = (const float4*)(x + (size_t)t * K_DIM);
    uint2* xbp = (uint2*)(xb + (size_t)t * K_DIM);   // 4 bf16 per uint2
    float acc[NEXP];
    #pragma unroll
    for (int e = 0; e < NEXP; ++e) acc[e] = 0.f;

    #pragma unroll 4
    for (int it = 0; it < K_DIM / 256; ++it) {
        float4 xv = xp[it * 64 + lane];
        union { bf16_t h[4]; uint2 u; } cv;
        cv.h[0] = (bf16_t)xv.x; cv.h[1] = (bf16_t)xv.y;
        cv.h[2] = (bf16_t)xv.z; cv.h[3] = (bf16_t)xv.w;
        xbp[it * 64 + lane] = cv.u;
        #pragma unroll
        for (int e = 0; e < NEXP; ++e) {
            float4 wv = ((const float4*)(routeW + (size_t)e * K_DIM))[it * 64 + lane];
            acc[e] += xv.x * wv.x + xv.y * wv.y + xv.z * wv.z + xv.w * wv.w;
        }
    }
    #pragma unroll
    for (int e = 0; e < NEXP; ++e)
        for (int off = 32; off > 0; off >>= 1)
            acc[e] += __shfl_xor(acc[e], off, 64);

    if (lane == 0) {
        float mx = acc[0];
        #pragma unroll
        for (int e = 1; e < NEXP; ++e) mx = fmaxf(mx, acc[e]);
        float p[NEXP], s = 0.f;
        #pragma unroll
        for (int e = 0; e < NEXP; ++e) { p[e] = expf(acc[e] - mx); s += p[e]; }
        float inv_s = 1.0f / s;
        #pragma unroll
        for (int e = 0; e < NEXP; ++e) p[e] *= inv_s;
        int i0 = 0;
        #pragma unroll
        for (int e = 1; e < NEXP; ++e) if (p[e] > p[i0]) i0 = e;
        int i1 = (i0 == 0) ? 1 : 0;
        #pragma unroll
        for (int e = 0; e < NEXP; ++e) { if (e == i0 || e == i1) continue; if (p[e] > p[i1]) i1 = e; }
        float v0 = p[i0], v1 = p[i1];
        float inv = 1.0f / (v0 + v1 + 1e-9f);
        float r[NEXP];
        #pragma unroll
        for (int e = 0; e < NEXP; ++e) r[e] = 0.f;
        r[i0] = v0 * inv; r[i1] = v1 * inv;
        #pragma unroll
        for (int e = 0; e < NEXP; ++e) {
            gate_out[(size_t)t * NEXP + e] = acc[e];
            rw_out[(size_t)t * NEXP + e]  = r[e];
        }
    }
}

// ---------------------------------------------------------------- K2: h = xb @ aflat^T gated -> hw bf16
// v2: BM=32, BN=128, BK=64 -> 256 blocks (one per CU), all 256 lanes DMA-active.

__global__ __launch_bounds__(256) void h_kernel_fast(const bf16_t* __restrict__ xb,
                                                     const bf16_t* __restrict__ aflat, // [128][4096] bf16
                                                     const float* __restrict__ rw,
                                                     bf16_t* __restrict__ hw)
{
    __shared__ bf16_t As[32 * 64];    // 4 KB
    __shared__ bf16_t Bs[128 * 64];   // 16 KB
    int tid = threadIdx.x, lane = tid & 63, wave = tid >> 6;
    int lrow = lane & 15, lq = lane >> 4;
    int n0 = wave * 32;
    int m0 = blockIdx.x * 32;
    floatx4 acc[2][2] = {};

    int r0 = tid >> 3;                // 0..31
    int c0 = (tid & 7) * 8;           // 0..56
    const bf16_t* gA = xb + (size_t)(m0 + r0) * K_DIM + c0;
    bf16_t* lA = As + wave * 512;     // wave-uniform; bytes = wave*1024

    for (int k0 = 0; k0 < K_DIM; k0 += 64) {
        GLOAD_LDS16(gA + k0, lA);
        #pragma unroll
        for (int i = 0; i < 4; ++i) {
            const bf16_t* gB = aflat + (size_t)(i * 32 + r0) * K_DIM + c0 + k0;
            GLOAD_LDS16(gB, Bs + i * 2048 + wave * 512);
        }
        __syncthreads();
        #pragma unroll
        for (int ks = 0; ks < 2; ++ks) {
            bf16x8 af[2], bfr[2];
            #pragma unroll
            for (int mi = 0; mi < 2; ++mi)
                af[mi] = *(const bf16x8*)(As + (mi * 16 + lrow) * 64 + ks * 32 + lq * 8);
            #pragma unroll
            for (int ni = 0; ni < 2; ++ni)
                bfr[ni] = *(const bf16x8*)(Bs + (n0 + ni * 16 + lrow) * 64 + ks * 32 + lq * 8);
            #pragma unroll
            for (int mi = 0; mi < 2; ++mi)
                #pragma unroll
                for (int ni = 0; ni < 2; ++ni)
                    acc[mi][ni] = __builtin_amdgcn_mfma_f32_16x16x32_bf16(af[mi], bfr[ni], acc[mi][ni], 0, 0, 0);
        }
        __syncthreads();
    }
    #pragma unroll
    for (int mi = 0; mi < 2; ++mi)
        #pragma unroll
        for (int ni = 0; ni < 2; ++ni)
            #pragma unroll
            for (int reg = 0; reg < 4; ++reg) {
                int t = m0 + mi * 16 + lq * 4 + reg;
                int j = n0 + ni * 16 + lrow;
                float g = rw[(size_t)t * NEXP + (j >> 4)] * SCALING;
                hw[(size_t)t * KEXT + j] = (bf16_t)(acc[mi][ni][reg] * g);
            }
}

// ---------------------------------------------------------------- K3: result = xb@Wb^T + bias + hw@bflat^T
// 128x128 tile, BK=32, async staging (m97 structure). Unchanged from round 2.

__global__ __launch_bounds__(256) void main_gemm_fast(const bf16_t* __restrict__ xb,
                                                      const bf16_t* __restrict__ Wb,
                                                      const float* __restrict__ bias,
                                                      const bf16_t* __restrict__ hw,
                                                      const bf16_t* __restrict__ bflat,
                                                      float* __restrict__ out)
{
    __shared__ bf16_t As[128 * 32];
    __shared__ bf16_t Bs[128 * 32];
    int tid = threadIdx.x, lane = tid & 63, wave = tid >> 6;
    int lrow = lane & 15, lq = lane >> 4;
    int wm = (wave >> 1) * 64, wn = (wave & 1) * 64;
    int tm = blockIdx.y * 128, tn = blockIdx.x * 128;
    floatx4 acc[4][4] = {};

    int r0 = tid >> 2;
    int cg = (tid & 3) * 8;
    const bf16_t* gA0 = xb + (size_t)(tm + r0) * K_DIM + cg;
    const bf16_t* gA1 = xb + (size_t)(tm + 64 + r0) * K_DIM + cg;
    const bf16_t* gB0 = Wb + (size_t)(tn + r0) * K_DIM + cg;
    const bf16_t* gB1 = Wb + (size_t)(tn + 64 + r0) * K_DIM + cg;
    bf16_t* lA0 = As + wave * 512;
    bf16_t* lA1 = As + 2048 + wave * 512;
    bf16_t* lB0 = Bs + wave * 512;
    bf16_t* lB1 = Bs + 2048 + wave * 512;

    for (int k0 = 0; k0 < K_DIM; k0 += 32) {
        GLOAD_LDS16(gA0 + k0, lA0);
        GLOAD_LDS16(gA1 + k0, lA1);
        GLOAD_LDS16(gB0 + k0, lB0);
        GLOAD_LDS16(gB1 + k0, lB1);
        __syncthreads();
        bf16x8 af[4], bfr[4];
        #pragma unroll
        for (int mi = 0; mi < 4; ++mi) af[mi] = *(const bf16x8*)(As + (wm + mi * 16 + lrow) * 32 + lq * 8);
        #pragma unroll
        for (int ni = 0; ni < 4; ++ni) bfr[ni] = *(const bf16x8*)(Bs + (wn + ni * 16 + lrow) * 32 + lq * 8);
        #pragma unroll
        for (int mi = 0; mi < 4; ++mi)
            #pragma unroll
            for (int ni = 0; ni < 4; ++ni)
                acc[mi][ni] = __builtin_amdgcn_mfma_f32_16x16x32_bf16(af[mi], bfr[ni], acc[mi][ni], 0, 0, 0);
        __syncthreads();
    }

    {
        const bf16_t* eA0 = hw    + (size_t)(tm + r0) * KEXT + cg;
        const bf16_t* eA1 = hw    + (size_t)(tm + 64 + r0) * KEXT + cg;
        const bf16_t* eB0 = bflat + (size_t)(tn + r0) * KEXT + cg;
        const bf16_t* eB1 = bflat + (size_t)(tn + 64 + r0) * KEXT + cg;
        for (int k0 = 0; k0 < KEXT; k0 += 32) {
            GLOAD_LDS16(eA0 + k0, lA0);
            GLOAD_LDS16(eA1 + k0, lA1);
            GLOAD_LDS16(eB0 + k0, lB0);
            GLOAD_LDS16(eB1 + k0, lB1);
            __syncthreads();
            bf16x8 af[4], bfr[4];
            #pragma unroll
            for (int mi = 0; mi < 4; ++mi) af[mi] = *(const bf16x8*)(As + (wm + mi * 16 + lrow) * 32 + lq * 8);
            #pragma unroll
            for (int ni = 0; ni < 4; ++ni) bfr[ni] = *(const bf16x8*)(Bs + (wn + ni * 16 + lrow) * 32 + lq * 8);
            #pragma unroll
            for (int mi = 0; mi < 4; ++mi)
                #pragma unroll
                for (int ni = 0; ni < 4; ++ni)
                    acc[mi][ni] = __builtin_amdgcn_mfma_f32_16x16x32_bf16(af[mi], bfr[ni], acc[mi][ni], 0, 0, 0);
            __syncthreads();
        }
    }

    #pragma unroll
    for (int mi = 0; mi < 4; ++mi)
        #pragma unroll
        for (int ni = 0; ni < 4; ++ni) {
            int row = tm + wm + mi * 16 + lq * 4;
            int col = tn + wn + ni * 16 + lrow;
            float b = bias[col];
            #pragma unroll
            for (int reg = 0; reg < 4; ++reg)
                out[(size_t)(row + reg) * N_OUT + col] = acc[mi][ni][reg] + b;
        }
}

// ================================================================ FALLBACK PATH (round-1, known-good)

__global__ __launch_bounds__(256) void gate_kernel(const float* __restrict__ x,
                                                   const float* __restrict__ routeW,
                                                   float* __restrict__ rw_out,
                                                   float* __restrict__ gate_out)
{
    int wave = threadIdx.x >> 6;
    int lane = threadIdx.x & 63;
    int t = blockIdx.x * 4 + wave;
    const float4* xp = (const float4*)(x + (size_t)t * K_DIM);
    float acc[NEXP];
    #pragma unroll
    for (int e = 0; e < NEXP; ++e) acc[e] = 0.f;
    #pragma unroll 4
    for (int it = 0; it < K_DIM / 256; ++it) {
        float4 xv = xp[it * 64 + lane];
        #pragma unroll
        for (int e = 0; e < NEXP; ++e) {
            float4 wv = ((const float4*)(routeW + (size_t)e * K_DIM))[it * 64 + lane];
            acc[e] += xv.x * wv.x + xv.y * wv.y + xv.z * wv.z + xv.w * wv.w;
        }
    }
    #pragma unroll
    for (int e = 0; e < NEXP; ++e)
        for (int off = 32; off > 0; off >>= 1)
            acc[e] += __shfl_xor(acc[e], off, 64);
    if (lane == 0) {
        float mx = acc[0];
        #pragma unroll
        for (int e = 1; e < NEXP; ++e) mx = fmaxf(mx, acc[e]);
        float p[NEXP], s = 0.f;
        #pragma unroll
        for (int e = 0; e < NEXP; ++e) { p[e] = expf(acc[e] - mx); s += p[e]; }
        float inv_s = 1.0f / s;
        #pragma unroll
        for (int e = 0; e < NEXP; ++e) p[e] *= inv_s;
        int i0 = 0;
        #pragma unroll
        for (int e = 1; e < NEXP; ++e) if (p[e] > p[i0]) i0 = e;
        int i1 = (i0 == 0) ? 1 : 0;
        #pragma unroll
        for (int e = 0; e < NEXP; ++e) { if (e == i0 || e == i1) continue; if (p[e] > p[i1]) i1 = e; }
        float v0 = p[i0], v1 = p[i1];
        float inv = 1.0f / (v0 + v1 + 1e-9f);
        float r[NEXP];
        #pragma unroll
        for (int e = 0; e < NEXP; ++e) r[e] = 0.f;
        r[i0] = v0 * inv; r[i1] = v1 * inv;
        #pragma unroll
        for (int e = 0; e < NEXP; ++e) {
            gate_out[(size_t)t * NEXP + e] = acc[e];
            rw_out[(size_t)t * NEXP + e]  = r[e];
        }
    }
}

__global__ __launch_bounds__(256) void h_kernel(const float* __restrict__ x,
                                                const float* __restrict__ loraA,
                                                const float* __restrict__ rw,
                                                bf16_t* __restrict__ hw)
{
    __shared__ bf16_t As[32][40];
    __shared__ bf16_t Bs[128][40];
    int tid = threadIdx.x;
    int wave = tid >> 6, lane = tid & 63;
    int lrow = lane & 15, lq = lane >> 4;
    int m0 = blockIdx.x * 32;
    floatx4 acc[2][2] = {};
    int rb = tid >> 1, cb = (tid & 1) * 16;
    for (int k0 = 0; k0 < K_DIM; k0 += 32) {
        if (tid < 64) {
            const float* srcA = x + (size_t)(m0 + rb) * K_DIM + k0 + cb;
            #pragma unroll
            for (int q = 0; q < 4; ++q) pack4(&As[rb][cb + q * 4], ((const float4*)srcA)[q]);
        }
        {
            const float* srcB = loraA + (size_t)rb * K_DIM + k0 + cb;
            #pragma unroll
            for (int q = 0; q < 4; ++q) pack4(&Bs[rb][cb + q * 4], ((const float4*)srcB)[q]);
        }
        __syncthreads();
        bf16x8 af[2], bfr[2];
        #pragma unroll
        for (int mi = 0; mi < 2; ++mi) af[mi] = *(const bf16x8*)&As[mi * 16 + lrow][lq * 8];
        #pragma unroll
        for (int ni = 0; ni < 2; ++ni) bfr[ni] = *(const bf16x8*)&Bs[wave * 32 + ni * 16 + lrow][lq * 8];
        #pragma unroll
        for (int mi = 0; mi < 2; ++mi)
            #pragma unroll
            for (int ni = 0; ni < 2; ++ni)
                acc[mi][ni] = __builtin_amdgcn_mfma_f32_16x16x32_bf16(af[mi], bfr[ni], acc[mi][ni], 0, 0, 0);
        __syncthreads();
    }
    #pragma unroll
    for (int mi = 0; mi < 2; ++mi)
        #pragma unroll
        for (int ni = 0; ni < 2; ++ni)
            #pragma unroll
            for (int reg = 0; reg < 4; ++reg) {
                int t = m0 + mi * 16 + lq * 4 + reg;
                int j = wave * 32 + ni * 16 + lrow;
                float g = rw[(size_t)t * NEXP + (j >> 4)] * SCALING;
                hw[(size_t)t * KEXT + j] = (bf16_t)(acc[mi][ni][reg] * g);
            }
}

__device__ __forceinline__ void mma_step(const bf16_t (*As)[40], const bf16_t (*Bs)[40],
                                         floatx4 acc[4][4], int wm, int wn, int lrow, int lq) {
    bf16x8 af[4], bfr[4];
    #pragma unroll
    for (int mi = 0; mi < 4; ++mi) af[mi] = *(const bf16x8*)&As[wm + mi * 16 + lrow][lq * 8];
    #pragma unroll
    for (int ni = 0; ni < 4; ++ni) bfr[ni] = *(const bf16x8*)&Bs[wn + ni * 16 + lrow][lq * 8];
    #pragma unroll
    for (int mi = 0; mi < 4; ++mi)
        #pragma unroll
        for (int ni = 0; ni < 4; ++ni)
            acc[mi][ni] = __builtin_amdgcn_mfma_f32_16x16x32_bf16(af[mi], bfr[ni], acc[mi][ni], 0, 0, 0);
}

__global__ __launch_bounds__(256) void main_gemm(const float* __restrict__ x,
                                                 const float* __restrict__ W,
                                                 const float* __restrict__ bias,
                                                 const bf16_t* __restrict__ hw,
                                                 const bf16_t* __restrict__ bflat,
                                                 float* __restrict__ out)
{
    __shared__ bf16_t As[128][40];
    __shared__ bf16_t Bs[128][40];
    int tid = threadIdx.x, lane = tid & 63, wave = tid >> 6;
    int lrow = lane & 15, lq = lane >> 4;
    int wm = (wave >> 1) * 64, wn = (wave & 1) * 64;
    int tm = blockIdx.y * 128, tn = blockIdx.x * 128;
    floatx4 acc[4][4] = {};
    int rb = tid >> 1, cb = (tid & 1) * 16;
    const float* gA = x + (size_t)(tm + rb) * K_DIM + cb;
    const float* gB = W + (size_t)(tn + rb) * K_DIM + cb;
    for (int k0 = 0; k0 < K_DIM; k0 += 32) {
        #pragma unroll
        for (int q = 0; q < 4; ++q) {
            pack4(&As[rb][cb + q * 4], ((const float4*)(gA + k0))[q]);
            pack4(&Bs[rb][cb + q * 4], ((const float4*)(gB + k0))[q]);
        }
        __syncthreads();
        mma_step(As, Bs, acc, wm, wn, lrow, lq);
        __syncthreads();
    }
    const bf16_t* eA = hw    + (size_t)(tm + rb) * KEXT + cb;
    const bf16_t* eB = bflat + (size_t)(tn + rb) * KEXT + cb;
    for (int k0 = 0; k0 < KEXT; k0 += 32) {
        *(uint4*)&As[rb][cb]     = *(const uint4*)(eA + k0);
        *(uint4*)&As[rb][cb + 8] = *(const uint4*)(eA + k0 + 8);
        *(uint4*)&Bs[rb][cb]     = *(const uint4*)(eB + k0);
        *(uint4*)&Bs[rb][cb + 8] = *(const uint4*)(eB + k0 + 8);
        __syncthreads();
        mma_step(As, Bs, acc, wm, wn, lrow, lq);
        __syncthreads();
    }
    #pragma unroll
    for (int mi = 0; mi < 4; ++mi)
        #pragma unroll
        for (int ni = 0; ni < 4; ++ni) {
            int row = tm + wm + mi * 16 + lq * 4;
            int col = tn + wn + ni * 16 + lrow;
            float b = bias[col];
            #pragma unroll
            for (int reg = 0; reg < 4; ++reg)
                out[(size_t)(row + reg) * N_OUT + col] = acc[mi][ni][reg] + b;
        }
}

// ---------------------------------------------------------------- launch

extern "C" void kernel_launch(void* const* d_in, const int* in_sizes, int n_in,
                              void* d_out, int out_size, void* d_ws, size_t ws_size,
                              hipStream_t stream) {
    const float* x      = (const float*)d_in[0];
    const float* W      = (const float*)d_in[1];
    const float* bias   = (const float*)d_in[2];
    const float* routeW = (const float*)d_in[3];
    const float* loraA  = (const float*)d_in[4];   // [8][16][4096] == [128][4096]
    const float* loraB  = (const float*)d_in[5];   // [8][4096][16]

    float* out0 = (float*)d_out;
    float* out1 = out0 + (size_t)M_TOK * N_OUT;
    float* out2 = out1 + (size_t)M_TOK * NEXP;

    size_t need = ((size_t)M_TOK * K_DIM + (size_t)N_OUT * K_DIM +
                   (size_t)KEXT * K_DIM + (size_t)N_OUT * KEXT +
                   (size_t)M_TOK * KEXT) * sizeof(bf16_t);

    if (ws_size >= need) {
        bf16_t* xb    = (bf16_t*)d_ws;
        bf16_t* Wb    = xb + (size_t)M_TOK * K_DIM;
        bf16_t* aflat = Wb + (size_t)N_OUT * K_DIM;
        bf16_t* bflat = aflat + (size_t)KEXT * K_DIM;
        bf16_t* hw    = bflat + (size_t)N_OUT * KEXT;

        hipLaunchKernelGGL(cvt_bf16, dim3((N_OUT * (size_t)K_DIM) / 8 / 256), dim3(256), 0, stream, W, Wb);
        hipLaunchKernelGGL(cvt_bf16, dim3((KEXT * (size_t)K_DIM) / 8 / 256), dim3(256), 0, stream, loraA, aflat);
        hipLaunchKernelGGL(prep_bflat, dim3((N_OUT * KEXT) / 256), dim3(256), 0, stream, loraB, bflat);
        hipLaunchKernelGGL(gate_cvt_kernel, dim3(M_TOK / 4), dim3(256), 0, stream, x, routeW, xb, out1, out2);
        hipLaunchKernelGGL(h_kernel_fast, dim3(M_TOK / 32), dim3(256), 0, stream, xb, aflat, out1, hw);
        hipLaunchKernelGGL(main_gemm_fast, dim3(N_OUT / 128, M_TOK / 128), dim3(256), 0, stream,
                           xb, Wb, bias, hw, bflat, out0);
    } else {
        bf16_t* bflat = (bf16_t*)d_ws;
        bf16_t* hw    = bflat + (size_t)N_OUT * KEXT;
        hipLaunchKernelGGL(prep_bflat, dim3((N_OUT * KEXT) / 256), dim3(256), 0, stream, loraB, bflat);
        hipLaunchKernelGGL(gate_kernel, dim3(M_TOK / 4), dim3(256), 0, stream, x, routeW, out1, out2);
        hipLaunchKernelGGL(h_kernel, dim3(M_TOK / 32), dim3(256), 0, stream, x, loraA, out1, hw);
        hipLaunchKernelGGL(main_gemm, dim3(N_OUT / 128, M_TOK / 128), dim3(256), 0, stream,
                           x, W, bias, hw, bflat, out0);
    }
}

// Round 4
// 695.030 us; speedup vs baseline: 1.5556x; 1.0641x over previous
//
#include <hip/hip_runtime.h>
#include <hip/hip_bf16.h>

typedef __bf16 bf16_t;
typedef __bf16 bf16x8 __attribute__((ext_vector_type(8)));
typedef float floatx4 __attribute__((ext_vector_type(4)));

#define M_TOK 8192
#define K_DIM 4096
#define N_OUT 4096
#define NEXP  8
#define LRANK 16
#define KEXT  128
#define SCALING 2.0f

// async 16B global -> LDS. LDS arg is wave-uniform base; HW scatters lane i to base + i*16B.
#define GLOAD_LDS16(g, l) \
    __builtin_amdgcn_global_load_lds((const __attribute__((address_space(1))) void*)(g), \
                                     (__attribute__((address_space(3))) void*)(l), 16, 0, 0)

// ---------------------------------------------------------------- helpers

__device__ __forceinline__ void pack4(bf16_t* dst, float4 v) {
    union { bf16_t h[4]; uint2 u; } t;
    t.h[0] = (bf16_t)v.x; t.h[1] = (bf16_t)v.y;
    t.h[2] = (bf16_t)v.z; t.h[3] = (bf16_t)v.w;
    *(uint2*)dst = t.u;
}

__device__ __forceinline__ void cvt8_body(const float* __restrict__ src,
                                          bf16_t* __restrict__ dst, int blk) {
    size_t i = (size_t)blk * 256 + threadIdx.x;
    float4 a = ((const float4*)src)[i * 2];
    float4 b = ((const float4*)src)[i * 2 + 1];
    union { bf16_t h[8]; uint4 u; } t;
    t.h[0] = (bf16_t)a.x; t.h[1] = (bf16_t)a.y; t.h[2] = (bf16_t)a.z; t.h[3] = (bf16_t)a.w;
    t.h[4] = (bf16_t)b.x; t.h[5] = (bf16_t)b.y; t.h[6] = (bf16_t)b.z; t.h[7] = (bf16_t)b.w;
    ((uint4*)dst)[i] = t.u;
}

// ---------------------------------------------------------------- prep_all: cvt W + cvt loraA + repack loraB
// grid = 8192 (W) + 256 (loraA) + 2048 (bflat) = 10496 blocks

#define PREP_W_BLKS   8192
#define PREP_A_BLKS   256
#define PREP_B_BLKS   2048

__global__ __launch_bounds__(256) void prep_all(const float* __restrict__ W,
                                                const float* __restrict__ loraA,
                                                const float* __restrict__ loraB,
                                                bf16_t* __restrict__ Wb,
                                                bf16_t* __restrict__ aflat,
                                                bf16_t* __restrict__ bflat) {
    int b = blockIdx.x;
    if (b < PREP_W_BLKS) {
        cvt8_body(W, Wb, b);
    } else if (b < PREP_W_BLKS + PREP_A_BLKS) {
        cvt8_body(loraA, aflat, b - PREP_W_BLKS);
    } else {
        int g = (b - PREP_W_BLKS - PREP_A_BLKS) * 256 + threadIdx.x;  // < 4096*128
        int o = g >> 7, j = g & 127;
        int e = j >> 4, r = j & 15;
        bflat[g] = (bf16_t)loraB[((size_t)e * N_OUT + o) * LRANK + r];
    }
}

// ---------------------------------------------------------------- gate_cvt16: router (fp32) + x->bf16
// 512 blocks x 256 thr; 16 tokens/block; routeW staged in LDS per 256-K chunk.

__global__ __launch_bounds__(256) void gate_cvt16(const float* __restrict__ x,
                                                  const float* __restrict__ routeW,
                                                  bf16_t* __restrict__ xb,
                                                  float* __restrict__ rw_out,    // [M,8]
                                                  float* __restrict__ gate_out)  // [M,8]
{
    __shared__ float rwT[NEXP][256];   // 8 KB
    int tid = threadIdx.x, lane = tid & 63, wave = tid >> 6;
    int tl = lane >> 4, seg = lane & 15;
    int t = blockIdx.x * 16 + wave * 4 + tl;     // this lane's token
    const float* xrow = x + (size_t)t * K_DIM;
    bf16_t* xbrow = xb + (size_t)t * K_DIM;

    float acc[NEXP];
    #pragma unroll
    for (int e = 0; e < NEXP; ++e) acc[e] = 0.f;

    int srow = tid >> 5, scol = (tid & 31) * 8;  // staging coords

    for (int kk = 0; kk < K_DIM / 256; ++kk) {
        // stage routeW[8][256] chunk
        {
            const float4* src = (const float4*)(routeW + (size_t)srow * K_DIM + kk * 256 + scol);
            float4 v0 = src[0], v1 = src[1];
            *(float4*)&rwT[srow][scol]     = v0;
            *(float4*)&rwT[srow][scol + 4] = v1;
        }
        __syncthreads();
        #pragma unroll
        for (int kc = 0; kc < 4; ++kc) {
            int kloc = kc * 64 + seg * 4;
            int k = kk * 256 + kloc;
            float4 xv = *(const float4*)(xrow + k);
            union { bf16_t h[4]; uint2 u; } cv;
            cv.h[0] = (bf16_t)xv.x; cv.h[1] = (bf16_t)xv.y;
            cv.h[2] = (bf16_t)xv.z; cv.h[3] = (bf16_t)xv.w;
            *(uint2*)(xbrow + k) = cv.u;
            #pragma unroll
            for (int e = 0; e < NEXP; ++e) {
                float4 wv = *(const float4*)&rwT[e][kloc];
                acc[e] += xv.x * wv.x + xv.y * wv.y + xv.z * wv.z + xv.w * wv.w;
            }
        }
        __syncthreads();
    }

    // reduce over the 16 lanes of this token
    #pragma unroll
    for (int e = 0; e < NEXP; ++e) {
        acc[e] += __shfl_xor(acc[e], 1);
        acc[e] += __shfl_xor(acc[e], 2);
        acc[e] += __shfl_xor(acc[e], 4);
        acc[e] += __shfl_xor(acc[e], 8);
    }

    if (seg == 0) {
        float mx = acc[0];
        #pragma unroll
        for (int e = 1; e < NEXP; ++e) mx = fmaxf(mx, acc[e]);
        float p[NEXP], s = 0.f;
        #pragma unroll
        for (int e = 0; e < NEXP; ++e) { p[e] = expf(acc[e] - mx); s += p[e]; }
        float inv_s = 1.0f / s;
        #pragma unroll
        for (int e = 0; e < NEXP; ++e) p[e] *= inv_s;
        int i0 = 0;
        #pragma unroll
        for (int e = 1; e < NEXP; ++e) if (p[e] > p[i0]) i0 = e;
        int i1 = (i0 == 0) ? 1 : 0;
        #pragma unroll
        for (int e = 0; e < NEXP; ++e) { if (e == i0 || e == i1) continue; if (p[e] > p[i1]) i1 = e; }
        float v0 = p[i0], v1 = p[i1];
        float inv = 1.0f / (v0 + v1 + 1e-9f);
        float r[NEXP];
        #pragma unroll
        for (int e = 0; e < NEXP; ++e) r[e] = 0.f;
        r[i0] = v0 * inv; r[i1] = v1 * inv;
        #pragma unroll
        for (int e = 0; e < NEXP; ++e) {
            gate_out[(size_t)t * NEXP + e] = acc[e];
            rw_out[(size_t)t * NEXP + e]  = r[e];
        }
    }
}

// ---------------------------------------------------------------- h_v3: h = xb @ aflat^T gated -> hw bf16
// BM=32, BN=128, BK=128, grid 256. Panel LDS layout [ks][row][32] keeps 64B rows (conflict-free).

__global__ __launch_bounds__(256) void h_kernel_v3(const bf16_t* __restrict__ xb,
                                                   const bf16_t* __restrict__ aflat, // [128][4096] bf16
                                                   const float* __restrict__ rw,
                                                   bf16_t* __restrict__ hw)
{
    __shared__ bf16_t As[4 * 32 * 32];    // 8 KB : panel ks, 32 rows, 32 elems
    __shared__ bf16_t Bs[4 * 128 * 32];   // 32 KB: panel ks, 128 rows, 32 elems
    int tid = threadIdx.x, lane = tid & 63, wave = tid >> 6;
    int lrow = lane & 15, lq = lane >> 4;
    int n0 = wave * 32;
    int m0 = blockIdx.x * 32;
    floatx4 acc[2][2] = {};

    // A DMA map: idx = i*256+tid -> ks=idx>>7, r=(idx>>2)&31, cc2=idx&3
    const bf16_t* srcA[2];
    #pragma unroll
    for (int i = 0; i < 2; ++i) {
        int idx = i * 256 + tid;
        int ks = idx >> 7, r = (idx >> 2) & 31, cc2 = idx & 3;
        srcA[i] = xb + (size_t)(m0 + r) * K_DIM + ks * 32 + cc2 * 8;
    }
    // B DMA map: idx = i*256+tid -> ks=idx>>9, r=(idx>>2)&127, cc2=idx&3
    const bf16_t* srcB[8];
    #pragma unroll
    for (int i = 0; i < 8; ++i) {
        int idx = i * 256 + tid;
        int ks = idx >> 9, r = (idx >> 2) & 127, cc2 = idx & 3;
        srcB[i] = aflat + (size_t)r * K_DIM + ks * 32 + cc2 * 8;
    }

    for (int k0 = 0; k0 < K_DIM; k0 += 128) {
        #pragma unroll
        for (int i = 0; i < 2; ++i)
            GLOAD_LDS16(srcA[i] + k0, (char*)As + (i * 256 + wave * 64) * 16);
        #pragma unroll
        for (int i = 0; i < 8; ++i)
            GLOAD_LDS16(srcB[i] + k0, (char*)Bs + (i * 256 + wave * 64) * 16);
        __syncthreads();
        #pragma unroll
        for (int ks = 0; ks < 4; ++ks) {
            bf16x8 af[2], bfr[2];
            #pragma unroll
            for (int mi = 0; mi < 2; ++mi)
                af[mi] = *(const bf16x8*)(As + ks * 1024 + (mi * 16 + lrow) * 32 + lq * 8);
            #pragma unroll
            for (int ni = 0; ni < 2; ++ni)
                bfr[ni] = *(const bf16x8*)(Bs + ks * 4096 + (n0 + ni * 16 + lrow) * 32 + lq * 8);
            #pragma unroll
            for (int mi = 0; mi < 2; ++mi)
                #pragma unroll
                for (int ni = 0; ni < 2; ++ni)
                    acc[mi][ni] = __builtin_amdgcn_mfma_f32_16x16x32_bf16(af[mi], bfr[ni], acc[mi][ni], 0, 0, 0);
        }
        __syncthreads();
    }
    #pragma unroll
    for (int mi = 0; mi < 2; ++mi)
        #pragma unroll
        for (int ni = 0; ni < 2; ++ni)
            #pragma unroll
            for (int reg = 0; reg < 4; ++reg) {
                int t = m0 + mi * 16 + lq * 4 + reg;
                int j = n0 + ni * 16 + lrow;
                float g = rw[(size_t)t * NEXP + (j >> 4)] * SCALING;
                hw[(size_t)t * KEXT + j] = (bf16_t)(acc[mi][ni][reg] * g);
            }
}

// ---------------------------------------------------------------- main GEMM (unchanged from round 2/3)

__global__ __launch_bounds__(256) void main_gemm_fast(const bf16_t* __restrict__ xb,
                                                      const bf16_t* __restrict__ Wb,
                                                      const float* __restrict__ bias,
                                                      const bf16_t* __restrict__ hw,
                                                      const bf16_t* __restrict__ bflat,
                                                      float* __restrict__ out)
{
    __shared__ bf16_t As[128 * 32];
    __shared__ bf16_t Bs[128 * 32];
    int tid = threadIdx.x, lane = tid & 63, wave = tid >> 6;
    int lrow = lane & 15, lq = lane >> 4;
    int wm = (wave >> 1) * 64, wn = (wave & 1) * 64;
    int tm = blockIdx.y * 128, tn = blockIdx.x * 128;
    floatx4 acc[4][4] = {};

    int r0 = tid >> 2;
    int cg = (tid & 3) * 8;
    const bf16_t* gA0 = xb + (size_t)(tm + r0) * K_DIM + cg;
    const bf16_t* gA1 = xb + (size_t)(tm + 64 + r0) * K_DIM + cg;
    const bf16_t* gB0 = Wb + (size_t)(tn + r0) * K_DIM + cg;
    const bf16_t* gB1 = Wb + (size_t)(tn + 64 + r0) * K_DIM + cg;
    bf16_t* lA0 = As + wave * 512;
    bf16_t* lA1 = As + 2048 + wave * 512;
    bf16_t* lB0 = Bs + wave * 512;
    bf16_t* lB1 = Bs + 2048 + wave * 512;

    for (int k0 = 0; k0 < K_DIM; k0 += 32) {
        GLOAD_LDS16(gA0 + k0, lA0);
        GLOAD_LDS16(gA1 + k0, lA1);
        GLOAD_LDS16(gB0 + k0, lB0);
        GLOAD_LDS16(gB1 + k0, lB1);
        __syncthreads();
        bf16x8 af[4], bfr[4];
        #pragma unroll
        for (int mi = 0; mi < 4; ++mi) af[mi] = *(const bf16x8*)(As + (wm + mi * 16 + lrow) * 32 + lq * 8);
        #pragma unroll
        for (int ni = 0; ni < 4; ++ni) bfr[ni] = *(const bf16x8*)(Bs + (wn + ni * 16 + lrow) * 32 + lq * 8);
        #pragma unroll
        for (int mi = 0; mi < 4; ++mi)
            #pragma unroll
            for (int ni = 0; ni < 4; ++ni)
                acc[mi][ni] = __builtin_amdgcn_mfma_f32_16x16x32_bf16(af[mi], bfr[ni], acc[mi][ni], 0, 0, 0);
        __syncthreads();
    }

    {
        const bf16_t* eA0 = hw    + (size_t)(tm + r0) * KEXT + cg;
        const bf16_t* eA1 = hw    + (size_t)(tm + 64 + r0) * KEXT + cg;
        const bf16_t* eB0 = bflat + (size_t)(tn + r0) * KEXT + cg;
        const bf16_t* eB1 = bflat + (size_t)(tn + 64 + r0) * KEXT + cg;
        for (int k0 = 0; k0 < KEXT; k0 += 32) {
            GLOAD_LDS16(eA0 + k0, lA0);
            GLOAD_LDS16(eA1 + k0, lA1);
            GLOAD_LDS16(eB0 + k0, lB0);
            GLOAD_LDS16(eB1 + k0, lB1);
            __syncthreads();
            bf16x8 af[4], bfr[4];
            #pragma unroll
            for (int mi = 0; mi < 4; ++mi) af[mi] = *(const bf16x8*)(As + (wm + mi * 16 + lrow) * 32 + lq * 8);
            #pragma unroll
            for (int ni = 0; ni < 4; ++ni) bfr[ni] = *(const bf16x8*)(Bs + (wn + ni * 16 + lrow) * 32 + lq * 8);
            #pragma unroll
            for (int mi = 0; mi < 4; ++mi)
                #pragma unroll
                for (int ni = 0; ni < 4; ++ni)
                    acc[mi][ni] = __builtin_amdgcn_mfma_f32_16x16x32_bf16(af[mi], bfr[ni], acc[mi][ni], 0, 0, 0);
            __syncthreads();
        }
    }

    #pragma unroll
    for (int mi = 0; mi < 4; ++mi)
        #pragma unroll
        for (int ni = 0; ni < 4; ++ni) {
            int row = tm + wm + mi * 16 + lq * 4;
            int col = tn + wn + ni * 16 + lrow;
            float b = bias[col];
            #pragma unroll
            for (int reg = 0; reg < 4; ++reg)
                out[(size_t)(row + reg) * N_OUT + col] = acc[mi][ni][reg] + b;
        }
}

// ================================================================ FALLBACK PATH (round-1, known-good)

__global__ __launch_bounds__(256) void prep_bflat(const float* __restrict__ loraB,
                                                  bf16_t* __restrict__ bflat) {
    int g = blockIdx.x * 256 + threadIdx.x;
    int o = g >> 7, j = g & 127;
    int e = j >> 4, r = j & 15;
    bflat[g] = (bf16_t)loraB[((size_t)e * N_OUT + o) * LRANK + r];
}

__global__ __launch_bounds__(256) void gate_kernel(const float* __restrict__ x,
                                                   const float* __restrict__ routeW,
                                                   float* __restrict__ rw_out,
                                                   float* __restrict__ gate_out)
{
    int wave = threadIdx.x >> 6;
    int lane = threadIdx.x & 63;
    int t = blockIdx.x * 4 + wave;
    const float4* xp = (const float4*)(x + (size_t)t * K_DIM);
    float acc[NEXP];
    #pragma unroll
    for (int e = 0; e < NEXP; ++e) acc[e] = 0.f;
    #pragma unroll 4
    for (int it = 0; it < K_DIM / 256; ++it) {
        float4 xv = xp[it * 64 + lane];
        #pragma unroll
        for (int e = 0; e < NEXP; ++e) {
            float4 wv = ((const float4*)(routeW + (size_t)e * K_DIM))[it * 64 + lane];
            acc[e] += xv.x * wv.x + xv.y * wv.y + xv.z * wv.z + xv.w * wv.w;
        }
    }
    #pragma unroll
    for (int e = 0; e < NEXP; ++e)
        for (int off = 32; off > 0; off >>= 1)
            acc[e] += __shfl_xor(acc[e], off, 64);
    if (lane == 0) {
        float mx = acc[0];
        #pragma unroll
        for (int e = 1; e < NEXP; ++e) mx = fmaxf(mx, acc[e]);
        float p[NEXP], s = 0.f;
        #pragma unroll
        for (int e = 0; e < NEXP; ++e) { p[e] = expf(acc[e] - mx); s += p[e]; }
        float inv_s = 1.0f / s;
        #pragma unroll
        for (int e = 0; e < NEXP; ++e) p[e] *= inv_s;
        int i0 = 0;
        #pragma unroll
        for (int e = 1; e < NEXP; ++e) if (p[e] > p[i0]) i0 = e;
        int i1 = (i0 == 0) ? 1 : 0;
        #pragma unroll
        for (int e = 0; e < NEXP; ++e) { if (e == i0 || e == i1) continue; if (p[e] > p[i1]) i1 = e; }
        float v0 = p[i0], v1 = p[i1];
        float inv = 1.0f / (v0 + v1 + 1e-9f);
        float r[NEXP];
        #pragma unroll
        for (int e = 0; e < NEXP; ++e) r[e] = 0.f;
        r[i0] = v0 * inv; r[i1] = v1 * inv;
        #pragma unroll
        for (int e = 0; e < NEXP; ++e) {
            gate_out[(size_t)t * NEXP + e] = acc[e];
            rw_out[(size_t)t * NEXP + e]  = r[e];
        }
    }
}

__global__ __launch_bounds__(256) void h_kernel(const float* __restrict__ x,
                                                const float* __restrict__ loraA,
                                                const float* __restrict__ rw,
                                                bf16_t* __restrict__ hw)
{
    __shared__ bf16_t As[32][40];
    __shared__ bf16_t Bs[128][40];
    int tid = threadIdx.x;
    int wave = tid >> 6, lane = tid & 63;
    int lrow = lane & 15, lq = lane >> 4;
    int m0 = blockIdx.x * 32;
    floatx4 acc[2][2] = {};
    int rb = tid >> 1, cb = (tid & 1) * 16;
    for (int k0 = 0; k0 < K_DIM; k0 += 32) {
        if (tid < 64) {
            const float* srcA = x + (size_t)(m0 + rb) * K_DIM + k0 + cb;
            #pragma unroll
            for (int q = 0; q < 4; ++q) pack4(&As[rb][cb + q * 4], ((const float4*)srcA)[q]);
        }
        {
            const float* srcB = loraA + (size_t)rb * K_DIM + k0 + cb;
            #pragma unroll
            for (int q = 0; q < 4; ++q) pack4(&Bs[rb][cb + q * 4], ((const float4*)srcB)[q]);
        }
        __syncthreads();
        bf16x8 af[2], bfr[2];
        #pragma unroll
        for (int mi = 0; mi < 2; ++mi) af[mi] = *(const bf16x8*)&As[mi * 16 + lrow][lq * 8];
        #pragma unroll
        for (int ni = 0; ni < 2; ++ni) bfr[ni] = *(const bf16x8*)&Bs[wave * 32 + ni * 16 + lrow][lq * 8];
        #pragma unroll
        for (int mi = 0; mi < 2; ++mi)
            #pragma unroll
            for (int ni = 0; ni < 2; ++ni)
                acc[mi][ni] = __builtin_amdgcn_mfma_f32_16x16x32_bf16(af[mi], bfr[ni], acc[mi][ni], 0, 0, 0);
        __syncthreads();
    }
    #pragma unroll
    for (int mi = 0; mi < 2; ++mi)
        #pragma unroll
        for (int ni = 0; ni < 2; ++ni)
            #pragma unroll
            for (int reg = 0; reg < 4; ++reg) {
                int t = m0 + mi * 16 + lq * 4 + reg;
                int j = wave * 32 + ni * 16 + lrow;
                float g = rw[(size_t)t * NEXP + (j >> 4)] * SCALING;
                hw[(size_t)t * KEXT + j] = (bf16_t)(acc[mi][ni][reg] * g);
            }
}

__device__ __forceinline__ void mma_step(const bf16_t (*As)[40], const bf16_t (*Bs)[40],
                                         floatx4 acc[4][4], int wm, int wn, int lrow, int lq) {
    bf16x8 af[4], bfr[4];
    #pragma unroll
    for (int mi = 0; mi < 4; ++mi) af[mi] = *(const bf16x8*)&As[wm + mi * 16 + lrow][lq * 8];
    #pragma unroll
    for (int ni = 0; ni < 4; ++ni) bfr[ni] = *(const bf16x8*)&Bs[wn + ni * 16 + lrow][lq * 8];
    #pragma unroll
    for (int mi = 0; mi < 4; ++mi)
        #pragma unroll
        for (int ni = 0; ni < 4; ++ni)
            acc[mi][ni] = __builtin_amdgcn_mfma_f32_16x16x32_bf16(af[mi], bfr[ni], acc[mi][ni], 0, 0, 0);
}

__global__ __launch_bounds__(256) void main_gemm(const float* __restrict__ x,
                                                 const float* __restrict__ W,
                                                 const float* __restrict__ bias,
                                                 const bf16_t* __restrict__ hw,
                                                 const bf16_t* __restrict__ bflat,
                                                 float* __restrict__ out)
{
    __shared__ bf16_t As[128][40];
    __shared__ bf16_t Bs[128][40];
    int tid = threadIdx.x, lane = tid & 63, wave = tid >> 6;
    int lrow = lane & 15, lq = lane >> 4;
    int wm = (wave >> 1) * 64, wn = (wave & 1) * 64;
    int tm = blockIdx.y * 128, tn = blockIdx.x * 128;
    floatx4 acc[4][4] = {};
    int rb = tid >> 1, cb = (tid & 1) * 16;
    const float* gA = x + (size_t)(tm + rb) * K_DIM + cb;
    const float* gB = W + (size_t)(tn + rb) * K_DIM + cb;
    for (int k0 = 0; k0 < K_DIM; k0 += 32) {
        #pragma unroll
        for (int q = 0; q < 4; ++q) {
            pack4(&As[rb][cb + q * 4], ((const float4*)(gA + k0))[q]);
            pack4(&Bs[rb][cb + q * 4], ((const float4*)(gB + k0))[q]);
        }
        __syncthreads();
        mma_step(As, Bs, acc, wm, wn, lrow, lq);
        __syncthreads();
    }
    const bf16_t* eA = hw    + (size_t)(tm + rb) * KEXT + cb;
    const bf16_t* eB = bflat + (size_t)(tn + rb) * KEXT + cb;
    for (int k0 = 0; k0 < KEXT; k0 += 32) {
        *(uint4*)&As[rb][cb]     = *(const uint4*)(eA + k0);
        *(uint4*)&As[rb][cb + 8] = *(const uint4*)(eA + k0 + 8);
        *(uint4*)&Bs[rb][cb]     = *(const uint4*)(eB + k0);
        *(uint4*)&Bs[rb][cb + 8] = *(const uint4*)(eB + k0 + 8);
        __syncthreads();
        mma_step(As, Bs, acc, wm, wn, lrow, lq);
        __syncthreads();
    }
    #pragma unroll
    for (int mi = 0; mi < 4; ++mi)
        #pragma unroll
        for (int ni = 0; ni < 4; ++ni) {
            int row = tm + wm + mi * 16 + lq * 4;
            int col = tn + wn + ni * 16 + lrow;
            float b = bias[col];
            #pragma unroll
            for (int reg = 0; reg < 4; ++reg)
                out[(size_t)(row + reg) * N_OUT + col] = acc[mi][ni][reg] + b;
        }
}

// ---------------------------------------------------------------- launch

extern "C" void kernel_launch(void* const* d_in, const int* in_sizes, int n_in,
                              void* d_out, int out_size, void* d_ws, size_t ws_size,
                              hipStream_t stream) {
    const float* x      = (const float*)d_in[0];
    const float* W      = (const float*)d_in[1];
    const float* bias   = (const float*)d_in[2];
    const float* routeW = (const float*)d_in[3];
    const float* loraA  = (const float*)d_in[4];   // [8][16][4096] == [128][4096]
    const float* loraB  = (const float*)d_in[5];   // [8][4096][16]

    float* out0 = (float*)d_out;
    float* out1 = out0 + (size_t)M_TOK * N_OUT;
    float* out2 = out1 + (size_t)M_TOK * NEXP;

    size_t need = ((size_t)M_TOK * K_DIM + (size_t)N_OUT * K_DIM +
                   (size_t)KEXT * K_DIM + (size_t)N_OUT * KEXT +
                   (size_t)M_TOK * KEXT) * sizeof(bf16_t);

    if (ws_size >= need) {
        bf16_t* xb    = (bf16_t*)d_ws;
        bf16_t* Wb    = xb + (size_t)M_TOK * K_DIM;
        bf16_t* aflat = Wb + (size_t)N_OUT * K_DIM;
        bf16_t* bflat = aflat + (size_t)KEXT * K_DIM;
        bf16_t* hw    = bflat + (size_t)N_OUT * KEXT;

        hipLaunchKernelGGL(prep_all, dim3(PREP_W_BLKS + PREP_A_BLKS + PREP_B_BLKS), dim3(256), 0, stream,
                           W, loraA, loraB, Wb, aflat, bflat);
        hipLaunchKernelGGL(gate_cvt16, dim3(M_TOK / 16), dim3(256), 0, stream, x, routeW, xb, out1, out2);
        hipLaunchKernelGGL(h_kernel_v3, dim3(M_TOK / 32), dim3(256), 0, stream, xb, aflat, out1, hw);
        hipLaunchKernelGGL(main_gemm_fast, dim3(N_OUT / 128, M_TOK / 128), dim3(256), 0, stream,
                           xb, Wb, bias, hw, bflat, out0);
    } else {
        bf16_t* bflat = (bf16_t*)d_ws;
        bf16_t* hw    = bflat + (size_t)N_OUT * KEXT;
        hipLaunchKernelGGL(prep_bflat, dim3((N_OUT * KEXT) / 256), dim3(256), 0, stream, loraB, bflat);
        hipLaunchKernelGGL(gate_kernel, dim3(M_TOK / 4), dim3(256), 0, stream, x, routeW, out1, out2);
        hipLaunchKernelGGL(h_kernel, dim3(M_TOK / 32), dim3(256), 0, stream, x, loraA, out1, hw);
        hipLaunchKernelGGL(main_gemm, dim3(N_OUT / 128, M_TOK / 128), dim3(256), 0, stream,
                           x, W, bias, hw, bflat, out0);
    }
}

// Round 5
// 605.766 us; speedup vs baseline: 1.7848x; 1.1474x over previous
//
#include <hip/hip_runtime.h>
#include <hip/hip_bf16.h>

typedef __bf16 bf16_t;
typedef __bf16 bf16x8 __attribute__((ext_vector_type(8)));
typedef float floatx4 __attribute__((ext_vector_type(4)));

#define M_TOK 8192
#define K_DIM 4096
#define N_OUT 4096
#define NEXP  8
#define LRANK 16
#define KEXT  128
#define SCALING 2.0f

// async 16B global -> LDS. LDS arg is wave-uniform base; HW scatters lane i to base + i*16B.
#define GLOAD_LDS16(g, l) \
    __builtin_amdgcn_global_load_lds((const __attribute__((address_space(1))) void*)(g), \
                                     (__attribute__((address_space(3))) void*)(l), 16, 0, 0)

// ---------------------------------------------------------------- helpers

__device__ __forceinline__ void pack4(bf16_t* dst, float4 v) {
    union { bf16_t h[4]; uint2 u; } t;
    t.h[0] = (bf16_t)v.x; t.h[1] = (bf16_t)v.y;
    t.h[2] = (bf16_t)v.z; t.h[3] = (bf16_t)v.w;
    *(uint2*)dst = t.u;
}

__device__ __forceinline__ void cvt8_body(const float* __restrict__ src,
                                          bf16_t* __restrict__ dst, int blk) {
    size_t i = (size_t)blk * 256 + threadIdx.x;
    float4 a = ((const float4*)src)[i * 2];
    float4 b = ((const float4*)src)[i * 2 + 1];
    union { bf16_t h[8]; uint4 u; } t;
    t.h[0] = (bf16_t)a.x; t.h[1] = (bf16_t)a.y; t.h[2] = (bf16_t)a.z; t.h[3] = (bf16_t)a.w;
    t.h[4] = (bf16_t)b.x; t.h[5] = (bf16_t)b.y; t.h[6] = (bf16_t)b.z; t.h[7] = (bf16_t)b.w;
    ((uint4*)dst)[i] = t.u;
}

// ---------------------------------------------------------------- prep_all: cvt W + cvt loraA + repack loraB

#define PREP_W_BLKS   8192
#define PREP_A_BLKS   256
#define PREP_B_BLKS   2048

__global__ __launch_bounds__(256) void prep_all(const float* __restrict__ W,
                                                const float* __restrict__ loraA,
                                                const float* __restrict__ loraB,
                                                bf16_t* __restrict__ Wb,
                                                bf16_t* __restrict__ aflat,
                                                bf16_t* __restrict__ bflat) {
    int b = blockIdx.x;
    if (b < PREP_W_BLKS) {
        cvt8_body(W, Wb, b);
    } else if (b < PREP_W_BLKS + PREP_A_BLKS) {
        cvt8_body(loraA, aflat, b - PREP_W_BLKS);
    } else {
        int g = (b - PREP_W_BLKS - PREP_A_BLKS) * 256 + threadIdx.x;  // < 4096*128
        int o = g >> 7, j = g & 127;
        int e = j >> 4, r = j & 15;
        bflat[g] = (bf16_t)loraB[((size_t)e * N_OUT + o) * LRANK + r];
    }
}

// ---------------------------------------------------------------- gate_cvt16: router (fp32) + x->bf16

__global__ __launch_bounds__(256) void gate_cvt16(const float* __restrict__ x,
                                                  const float* __restrict__ routeW,
                                                  bf16_t* __restrict__ xb,
                                                  float* __restrict__ rw_out,    // [M,8]
                                                  float* __restrict__ gate_out)  // [M,8]
{
    __shared__ float rwT[NEXP][256];   // 8 KB
    int tid = threadIdx.x, lane = tid & 63, wave = tid >> 6;
    int tl = lane >> 4, seg = lane & 15;
    int t = blockIdx.x * 16 + wave * 4 + tl;
    const float* xrow = x + (size_t)t * K_DIM;
    bf16_t* xbrow = xb + (size_t)t * K_DIM;

    float acc[NEXP];
    #pragma unroll
    for (int e = 0; e < NEXP; ++e) acc[e] = 0.f;

    int srow = tid >> 5, scol = (tid & 31) * 8;

    for (int kk = 0; kk < K_DIM / 256; ++kk) {
        {
            const float4* src = (const float4*)(routeW + (size_t)srow * K_DIM + kk * 256 + scol);
            float4 v0 = src[0], v1 = src[1];
            *(float4*)&rwT[srow][scol]     = v0;
            *(float4*)&rwT[srow][scol + 4] = v1;
        }
        __syncthreads();
        #pragma unroll
        for (int kc = 0; kc < 4; ++kc) {
            int kloc = kc * 64 + seg * 4;
            int k = kk * 256 + kloc;
            float4 xv = *(const float4*)(xrow + k);
            union { bf16_t h[4]; uint2 u; } cv;
            cv.h[0] = (bf16_t)xv.x; cv.h[1] = (bf16_t)xv.y;
            cv.h[2] = (bf16_t)xv.z; cv.h[3] = (bf16_t)xv.w;
            *(uint2*)(xbrow + k) = cv.u;
            #pragma unroll
            for (int e = 0; e < NEXP; ++e) {
                float4 wv = *(const float4*)&rwT[e][kloc];
                acc[e] += xv.x * wv.x + xv.y * wv.y + xv.z * wv.z + xv.w * wv.w;
            }
        }
        __syncthreads();
    }

    #pragma unroll
    for (int e = 0; e < NEXP; ++e) {
        acc[e] += __shfl_xor(acc[e], 1);
        acc[e] += __shfl_xor(acc[e], 2);
        acc[e] += __shfl_xor(acc[e], 4);
        acc[e] += __shfl_xor(acc[e], 8);
    }

    if (seg == 0) {
        float mx = acc[0];
        #pragma unroll
        for (int e = 1; e < NEXP; ++e) mx = fmaxf(mx, acc[e]);
        float p[NEXP], s = 0.f;
        #pragma unroll
        for (int e = 0; e < NEXP; ++e) { p[e] = expf(acc[e] - mx); s += p[e]; }
        float inv_s = 1.0f / s;
        #pragma unroll
        for (int e = 0; e < NEXP; ++e) p[e] *= inv_s;
        int i0 = 0;
        #pragma unroll
        for (int e = 1; e < NEXP; ++e) if (p[e] > p[i0]) i0 = e;
        int i1 = (i0 == 0) ? 1 : 0;
        #pragma unroll
        for (int e = 0; e < NEXP; ++e) { if (e == i0 || e == i1) continue; if (p[e] > p[i1]) i1 = e; }
        float v0 = p[i0], v1 = p[i1];
        float inv = 1.0f / (v0 + v1 + 1e-9f);
        float r[NEXP];
        #pragma unroll
        for (int e = 0; e < NEXP; ++e) r[e] = 0.f;
        r[i0] = v0 * inv; r[i1] = v1 * inv;
        #pragma unroll
        for (int e = 0; e < NEXP; ++e) {
            gate_out[(size_t)t * NEXP + e] = acc[e];
            rw_out[(size_t)t * NEXP + e]  = r[e];
        }
    }
}

// ---------------------------------------------------------------- h_v3 (unchanged from round 4)

__global__ __launch_bounds__(256) void h_kernel_v3(const bf16_t* __restrict__ xb,
                                                   const bf16_t* __restrict__ aflat,
                                                   const float* __restrict__ rw,
                                                   bf16_t* __restrict__ hw)
{
    __shared__ bf16_t As[4 * 32 * 32];
    __shared__ bf16_t Bs[4 * 128 * 32];
    int tid = threadIdx.x, lane = tid & 63, wave = tid >> 6;
    int lrow = lane & 15, lq = lane >> 4;
    int n0 = wave * 32;
    int m0 = blockIdx.x * 32;
    floatx4 acc[2][2] = {};

    const bf16_t* srcA[2];
    #pragma unroll
    for (int i = 0; i < 2; ++i) {
        int idx = i * 256 + tid;
        int ks = idx >> 7, r = (idx >> 2) & 31, cc2 = idx & 3;
        srcA[i] = xb + (size_t)(m0 + r) * K_DIM + ks * 32 + cc2 * 8;
    }
    const bf16_t* srcB[8];
    #pragma unroll
    for (int i = 0; i < 8; ++i) {
        int idx = i * 256 + tid;
        int ks = idx >> 9, r = (idx >> 2) & 127, cc2 = idx & 3;
        srcB[i] = aflat + (size_t)r * K_DIM + ks * 32 + cc2 * 8;
    }

    for (int k0 = 0; k0 < K_DIM; k0 += 128) {
        #pragma unroll
        for (int i = 0; i < 2; ++i)
            GLOAD_LDS16(srcA[i] + k0, (char*)As + (i * 256 + wave * 64) * 16);
        #pragma unroll
        for (int i = 0; i < 8; ++i)
            GLOAD_LDS16(srcB[i] + k0, (char*)Bs + (i * 256 + wave * 64) * 16);
        __syncthreads();
        #pragma unroll
        for (int ks = 0; ks < 4; ++ks) {
            bf16x8 af[2], bfr[2];
            #pragma unroll
            for (int mi = 0; mi < 2; ++mi)
                af[mi] = *(const bf16x8*)(As + ks * 1024 + (mi * 16 + lrow) * 32 + lq * 8);
            #pragma unroll
            for (int ni = 0; ni < 2; ++ni)
                bfr[ni] = *(const bf16x8*)(Bs + ks * 4096 + (n0 + ni * 16 + lrow) * 32 + lq * 8);
            #pragma unroll
            for (int mi = 0; mi < 2; ++mi)
                #pragma unroll
                for (int ni = 0; ni < 2; ++ni)
                    acc[mi][ni] = __builtin_amdgcn_mfma_f32_16x16x32_bf16(af[mi], bfr[ni], acc[mi][ni], 0, 0, 0);
        }
        __syncthreads();
    }
    #pragma unroll
    for (int mi = 0; mi < 2; ++mi)
        #pragma unroll
        for (int ni = 0; ni < 2; ++ni)
            #pragma unroll
            for (int reg = 0; reg < 4; ++reg) {
                int t = m0 + mi * 16 + lq * 4 + reg;
                int j = n0 + ni * 16 + lrow;
                float g = rw[(size_t)t * NEXP + (j >> 4)] * SCALING;
                hw[(size_t)t * KEXT + j] = (bf16_t)(acc[mi][ni][reg] * g);
            }
}

// ---------------------------------------------------------------- main GEMM v2: BK=64, XOR granule swizzle
// LDS: rows of 64 elems (128B = 8 granules of 16B). Physical granule pg = g ^ (row&7).
// Swizzle applied via source-pointer permutation (DMA scatter is fixed lane*16B).
// 64+2 K-iters, 32 MFMA per barrier pair.

__global__ __launch_bounds__(256) void main_gemm_v2(const bf16_t* __restrict__ xb,
                                                    const bf16_t* __restrict__ Wb,
                                                    const float* __restrict__ bias,
                                                    const bf16_t* __restrict__ hw,
                                                    const bf16_t* __restrict__ bflat,
                                                    float* __restrict__ out)
{
    __shared__ bf16_t As[128 * 64];   // 16 KB
    __shared__ bf16_t Bs[128 * 64];   // 16 KB
    int tid = threadIdx.x, lane = tid & 63, wave = tid >> 6;
    int lrow = lane & 15, lq = lane >> 4;
    int wm = (wave >> 1) * 64, wn = (wave & 1) * 64;
    int tm = blockIdx.y * 128, tn = blockIdx.x * 128;
    floatx4 acc[4][4] = {};

    // DMA source pointers with inverse swizzle: physical slot s holds logical (row, lg= (s&7)^(row&7))
    const bf16_t* srcA[4];
    const bf16_t* srcB[4];
    #pragma unroll
    for (int i = 0; i < 4; ++i) {
        int s = i * 256 + tid;
        int row = s >> 3;
        int lg = (s & 7) ^ (row & 7);
        srcA[i] = xb + (size_t)(tm + row) * K_DIM + lg * 8;
        srcB[i] = Wb + (size_t)(tn + row) * K_DIM + lg * 8;
    }

    // swizzled fragment granule offsets (elems): ((ks*4+lq)^(lrow&7))*8
    int swz = lrow & 7;

    for (int k0 = 0; k0 < K_DIM; k0 += 64) {
        #pragma unroll
        for (int i = 0; i < 4; ++i) {
            GLOAD_LDS16(srcA[i] + k0, (char*)As + i * 4096 + wave * 1024);
            GLOAD_LDS16(srcB[i] + k0, (char*)Bs + i * 4096 + wave * 1024);
        }
        __syncthreads();
        #pragma unroll
        for (int ks = 0; ks < 2; ++ks) {
            int go = ((ks * 4 + lq) ^ swz) * 8;
            bf16x8 af[4], bfr[4];
            #pragma unroll
            for (int mi = 0; mi < 4; ++mi)
                af[mi] = *(const bf16x8*)(As + (wm + mi * 16 + lrow) * 64 + go);
            #pragma unroll
            for (int ni = 0; ni < 4; ++ni)
                bfr[ni] = *(const bf16x8*)(Bs + (wn + ni * 16 + lrow) * 64 + go);
            #pragma unroll
            for (int mi = 0; mi < 4; ++mi)
                #pragma unroll
                for (int ni = 0; ni < 4; ++ni)
                    acc[mi][ni] = __builtin_amdgcn_mfma_f32_16x16x32_bf16(af[mi], bfr[ni], acc[mi][ni], 0, 0, 0);
        }
        __syncthreads();
    }

    // K-extension: 128 more K from hw (A) and bflat (B), row stride KEXT
    {
        const bf16_t* eA[4];
        const bf16_t* eB[4];
        #pragma unroll
        for (int i = 0; i < 4; ++i) {
            int s = i * 256 + tid;
            int row = s >> 3;
            int lg = (s & 7) ^ (row & 7);
            eA[i] = hw    + (size_t)(tm + row) * KEXT + lg * 8;
            eB[i] = bflat + (size_t)(tn + row) * KEXT + lg * 8;
        }
        for (int k0 = 0; k0 < KEXT; k0 += 64) {
            #pragma unroll
            for (int i = 0; i < 4; ++i) {
                GLOAD_LDS16(eA[i] + k0, (char*)As + i * 4096 + wave * 1024);
                GLOAD_LDS16(eB[i] + k0, (char*)Bs + i * 4096 + wave * 1024);
            }
            __syncthreads();
            #pragma unroll
            for (int ks = 0; ks < 2; ++ks) {
                int go = ((ks * 4 + lq) ^ swz) * 8;
                bf16x8 af[4], bfr[4];
                #pragma unroll
                for (int mi = 0; mi < 4; ++mi)
                    af[mi] = *(const bf16x8*)(As + (wm + mi * 16 + lrow) * 64 + go);
                #pragma unroll
                for (int ni = 0; ni < 4; ++ni)
                    bfr[ni] = *(const bf16x8*)(Bs + (wn + ni * 16 + lrow) * 64 + go);
                #pragma unroll
                for (int mi = 0; mi < 4; ++mi)
                    #pragma unroll
                    for (int ni = 0; ni < 4; ++ni)
                        acc[mi][ni] = __builtin_amdgcn_mfma_f32_16x16x32_bf16(af[mi], bfr[ni], acc[mi][ni], 0, 0, 0);
            }
            __syncthreads();
        }
    }

    #pragma unroll
    for (int mi = 0; mi < 4; ++mi)
        #pragma unroll
        for (int ni = 0; ni < 4; ++ni) {
            int row = tm + wm + mi * 16 + lq * 4;
            int col = tn + wn + ni * 16 + lrow;
            float b = bias[col];
            #pragma unroll
            for (int reg = 0; reg < 4; ++reg)
                out[(size_t)(row + reg) * N_OUT + col] = acc[mi][ni][reg] + b;
        }
}

// ================================================================ FALLBACK PATH (round-1, known-good)

__global__ __launch_bounds__(256) void prep_bflat(const float* __restrict__ loraB,
                                                  bf16_t* __restrict__ bflat) {
    int g = blockIdx.x * 256 + threadIdx.x;
    int o = g >> 7, j = g & 127;
    int e = j >> 4, r = j & 15;
    bflat[g] = (bf16_t)loraB[((size_t)e * N_OUT + o) * LRANK + r];
}

__global__ __launch_bounds__(256) void gate_kernel(const float* __restrict__ x,
                                                   const float* __restrict__ routeW,
                                                   float* __restrict__ rw_out,
                                                   float* __restrict__ gate_out)
{
    int wave = threadIdx.x >> 6;
    int lane = threadIdx.x & 63;
    int t = blockIdx.x * 4 + wave;
    const float4* xp = (const float4*)(x + (size_t)t * K_DIM);
    float acc[NEXP];
    #pragma unroll
    for (int e = 0; e < NEXP; ++e) acc[e] = 0.f;
    #pragma unroll 4
    for (int it = 0; it < K_DIM / 256; ++it) {
        float4 xv = xp[it * 64 + lane];
        #pragma unroll
        for (int e = 0; e < NEXP; ++e) {
            float4 wv = ((const float4*)(routeW + (size_t)e * K_DIM))[it * 64 + lane];
            acc[e] += xv.x * wv.x + xv.y * wv.y + xv.z * wv.z + xv.w * wv.w;
        }
    }
    #pragma unroll
    for (int e = 0; e < NEXP; ++e)
        for (int off = 32; off > 0; off >>= 1)
            acc[e] += __shfl_xor(acc[e], off, 64);
    if (lane == 0) {
        float mx = acc[0];
        #pragma unroll
        for (int e = 1; e < NEXP; ++e) mx = fmaxf(mx, acc[e]);
        float p[NEXP], s = 0.f;
        #pragma unroll
        for (int e = 0; e < NEXP; ++e) { p[e] = expf(acc[e] - mx); s += p[e]; }
        float inv_s = 1.0f / s;
        #pragma unroll
        for (int e = 0; e < NEXP; ++e) p[e] *= inv_s;
        int i0 = 0;
        #pragma unroll
        for (int e = 1; e < NEXP; ++e) if (p[e] > p[i0]) i0 = e;
        int i1 = (i0 == 0) ? 1 : 0;
        #pragma unroll
        for (int e = 0; e < NEXP; ++e) { if (e == i0 || e == i1) continue; if (p[e] > p[i1]) i1 = e; }
        float v0 = p[i0], v1 = p[i1];
        float inv = 1.0f / (v0 + v1 + 1e-9f);
        float r[NEXP];
        #pragma unroll
        for (int e = 0; e < NEXP; ++e) r[e] = 0.f;
        r[i0] = v0 * inv; r[i1] = v1 * inv;
        #pragma unroll
        for (int e = 0; e < NEXP; ++e) {
            gate_out[(size_t)t * NEXP + e] = acc[e];
            rw_out[(size_t)t * NEXP + e]  = r[e];
        }
    }
}

__global__ __launch_bounds__(256) void h_kernel(const float* __restrict__ x,
                                                const float* __restrict__ loraA,
                                                const float* __restrict__ rw,
                                                bf16_t* __restrict__ hw)
{
    __shared__ bf16_t As[32][40];
    __shared__ bf16_t Bs[128][40];
    int tid = threadIdx.x;
    int wave = tid >> 6, lane = tid & 63;
    int lrow = lane & 15, lq = lane >> 4;
    int m0 = blockIdx.x * 32;
    floatx4 acc[2][2] = {};
    int rb = tid >> 1, cb = (tid & 1) * 16;
    for (int k0 = 0; k0 < K_DIM; k0 += 32) {
        if (tid < 64) {
            const float* srcA = x + (size_t)(m0 + rb) * K_DIM + k0 + cb;
            #pragma unroll
            for (int q = 0; q < 4; ++q) pack4(&As[rb][cb + q * 4], ((const float4*)srcA)[q]);
        }
        {
            const float* srcB = loraA + (size_t)rb * K_DIM + k0 + cb;
            #pragma unroll
            for (int q = 0; q < 4; ++q) pack4(&Bs[rb][cb + q * 4], ((const float4*)srcB)[q]);
        }
        __syncthreads();
        bf16x8 af[2], bfr[2];
        #pragma unroll
        for (int mi = 0; mi < 2; ++mi) af[mi] = *(const bf16x8*)&As[mi * 16 + lrow][lq * 8];
        #pragma unroll
        for (int ni = 0; ni < 2; ++ni) bfr[ni] = *(const bf16x8*)&Bs[wave * 32 + ni * 16 + lrow][lq * 8];
        #pragma unroll
        for (int mi = 0; mi < 2; ++mi)
            #pragma unroll
            for (int ni = 0; ni < 2; ++ni)
                acc[mi][ni] = __builtin_amdgcn_mfma_f32_16x16x32_bf16(af[mi], bfr[ni], acc[mi][ni], 0, 0, 0);
        __syncthreads();
    }
    #pragma unroll
    for (int mi = 0; mi < 2; ++mi)
        #pragma unroll
        for (int ni = 0; ni < 2; ++ni)
            #pragma unroll
            for (int reg = 0; reg < 4; ++reg) {
                int t = m0 + mi * 16 + lq * 4 + reg;
                int j = wave * 32 + ni * 16 + lrow;
                float g = rw[(size_t)t * NEXP + (j >> 4)] * SCALING;
                hw[(size_t)t * KEXT + j] = (bf16_t)(acc[mi][ni][reg] * g);
            }
}

__device__ __forceinline__ void mma_step(const bf16_t (*As)[40], const bf16_t (*Bs)[40],
                                         floatx4 acc[4][4], int wm, int wn, int lrow, int lq) {
    bf16x8 af[4], bfr[4];
    #pragma unroll
    for (int mi = 0; mi < 4; ++mi) af[mi] = *(const bf16x8*)&As[wm + mi * 16 + lrow][lq * 8];
    #pragma unroll
    for (int ni = 0; ni < 4; ++ni) bfr[ni] = *(const bf16x8*)&Bs[wn + ni * 16 + lrow][lq * 8];
    #pragma unroll
    for (int mi = 0; mi < 4; ++mi)
        #pragma unroll
        for (int ni = 0; ni < 4; ++ni)
            acc[mi][ni] = __builtin_amdgcn_mfma_f32_16x16x32_bf16(af[mi], bfr[ni], acc[mi][ni], 0, 0, 0);
}

__global__ __launch_bounds__(256) void main_gemm(const float* __restrict__ x,
                                                 const float* __restrict__ W,
                                                 const float* __restrict__ bias,
                                                 const bf16_t* __restrict__ hw,
                                                 const bf16_t* __restrict__ bflat,
                                                 float* __restrict__ out)
{
    __shared__ bf16_t As[128][40];
    __shared__ bf16_t Bs[128][40];
    int tid = threadIdx.x, lane = tid & 63, wave = tid >> 6;
    int lrow = lane & 15, lq = lane >> 4;
    int wm = (wave >> 1) * 64, wn = (wave & 1) * 64;
    int tm = blockIdx.y * 128, tn = blockIdx.x * 128;
    floatx4 acc[4][4] = {};
    int rb = tid >> 1, cb = (tid & 1) * 16;
    const float* gA = x + (size_t)(tm + rb) * K_DIM + cb;
    const float* gB = W + (size_t)(tn + rb) * K_DIM + cb;
    for (int k0 = 0; k0 < K_DIM; k0 += 32) {
        #pragma unroll
        for (int q = 0; q < 4; ++q) {
            pack4(&As[rb][cb + q * 4], ((const float4*)(gA + k0))[q]);
            pack4(&Bs[rb][cb + q * 4], ((const float4*)(gB + k0))[q]);
        }
        __syncthreads();
        mma_step(As, Bs, acc, wm, wn, lrow, lq);
        __syncthreads();
    }
    const bf16_t* eA = hw    + (size_t)(tm + rb) * KEXT + cb;
    const bf16_t* eB = bflat + (size_t)(tn + rb) * KEXT + cb;
    for (int k0 = 0; k0 < KEXT; k0 += 32) {
        *(uint4*)&As[rb][cb]     = *(const uint4*)(eA + k0);
        *(uint4*)&As[rb][cb + 8] = *(const uint4*)(eA + k0 + 8);
        *(uint4*)&Bs[rb][cb]     = *(const uint4*)(eB + k0);
        *(uint4*)&Bs[rb][cb + 8] = *(const uint4*)(eB + k0 + 8);
        __syncthreads();
        mma_step(As, Bs, acc, wm, wn, lrow, lq);
        __syncthreads();
    }
    #pragma unroll
    for (int mi = 0; mi < 4; ++mi)
        #pragma unroll
        for (int ni = 0; ni < 4; ++ni) {
            int row = tm + wm + mi * 16 + lq * 4;
            int col = tn + wn + ni * 16 + lrow;
            float b = bias[col];
            #pragma unroll
            for (int reg = 0; reg < 4; ++reg)
                out[(size_t)(row + reg) * N_OUT + col] = acc[mi][ni][reg] + b;
        }
}

// ---------------------------------------------------------------- launch

extern "C" void kernel_launch(void* const* d_in, const int* in_sizes, int n_in,
                              void* d_out, int out_size, void* d_ws, size_t ws_size,
                              hipStream_t stream) {
    const float* x      = (const float*)d_in[0];
    const float* W      = (const float*)d_in[1];
    const float* bias   = (const float*)d_in[2];
    const float* routeW = (const float*)d_in[3];
    const float* loraA  = (const float*)d_in[4];   // [8][16][4096] == [128][4096]
    const float* loraB  = (const float*)d_in[5];   // [8][4096][16]

    float* out0 = (float*)d_out;
    float* out1 = out0 + (size_t)M_TOK * N_OUT;
    float* out2 = out1 + (size_t)M_TOK * NEXP;

    size_t need = ((size_t)M_TOK * K_DIM + (size_t)N_OUT * K_DIM +
                   (size_t)KEXT * K_DIM + (size_t)N_OUT * KEXT +
                   (size_t)M_TOK * KEXT) * sizeof(bf16_t);

    if (ws_size >= need) {
        bf16_t* xb    = (bf16_t*)d_ws;
        bf16_t* Wb    = xb + (size_t)M_TOK * K_DIM;
        bf16_t* aflat = Wb + (size_t)N_OUT * K_DIM;
        bf16_t* bflat = aflat + (size_t)KEXT * K_DIM;
        bf16_t* hw    = bflat + (size_t)N_OUT * KEXT;

        hipLaunchKernelGGL(prep_all, dim3(PREP_W_BLKS + PREP_A_BLKS + PREP_B_BLKS), dim3(256), 0, stream,
                           W, loraA, loraB, Wb, aflat, bflat);
        hipLaunchKernelGGL(gate_cvt16, dim3(M_TOK / 16), dim3(256), 0, stream, x, routeW, xb, out1, out2);
        hipLaunchKernelGGL(h_kernel_v3, dim3(M_TOK / 32), dim3(256), 0, stream, xb, aflat, out1, hw);
        hipLaunchKernelGGL(main_gemm_v2, dim3(N_OUT / 128, M_TOK / 128), dim3(256), 0, stream,
                           xb, Wb, bias, hw, bflat, out0);
    } else {
        bf16_t* bflat = (bf16_t*)d_ws;
        bf16_t* hw    = bflat + (size_t)N_OUT * KEXT;
        hipLaunchKernelGGL(prep_bflat, dim3((N_OUT * KEXT) / 256), dim3(256), 0, stream, loraB, bflat);
        hipLaunchKernelGGL(gate_kernel, dim3(M_TOK / 4), dim3(256), 0, stream, x, routeW, out1, out2);
        hipLaunchKernelGGL(h_kernel, dim3(M_TOK / 32), dim3(256), 0, stream, x, loraA, out1, hw);
        hipLaunchKernelGGL(main_gemm, dim3(N_OUT / 128, M_TOK / 128), dim3(256), 0, stream,
                           x, W, bias, hw, bflat, out0);
    }
}